// Round 6
// baseline (1062.496 us; speedup 1.0000x reference)
//
#include <hip/hip_runtime.h>
#include <cstdint>
#include <cstddef>

#define NN 8192
#define DD 512
#define HH 256
#define KTOP 21
#define CCAP 192   // candidate collection capacity
#define CMIN 48    // minimum candidates (superset of top-21 w/ bf16 margin)
#define ECAP 224   // per-row edge-list capacity
#define NBIN 1024

typedef __attribute__((ext_vector_type(8))) __bf16 bf16x8;
typedef __attribute__((ext_vector_type(4))) float f32x4;

__device__ __forceinline__ unsigned short f2bf(float x) {
    unsigned u = __float_as_uint(x);
    u += 0x7fffu + ((u >> 16) & 1u);
    return (unsigned short)(u >> 16);
}
__device__ __forceinline__ float bf2f(unsigned short h) {
    return __uint_as_float(((unsigned)h) << 16);
}
// order-preserving key: monotone map float -> uint (used by sort)
__device__ __forceinline__ unsigned ordkey(float x) {
    unsigned b = __float_as_uint(x);
    return b ^ (((int)b >> 31) | 0x80000000u);
}

#define GLD16(gp, lp) __builtin_amdgcn_global_load_lds( \
    (const __attribute__((address_space(1))) unsigned int*)(gp), \
    (__attribute__((address_space(3))) unsigned int*)(lp), 16, 0, 0)

// ---------------------------------------------------------------------------
// fp32 SGEMM: GEMM1/2 (emb path must stay fp32-exact for selection)
// ---------------------------------------------------------------------------
template<bool TRANSB, int ACT>
__global__ __launch_bounds__(256)
void sgemm128(const float* __restrict__ A, const float* __restrict__ B,
              const float* __restrict__ bias, float* __restrict__ C,
              int M, int N, int K) {
    constexpr int BM = 128, BN = 128, BK = 16;
    __shared__ float As[BK][BM + 4];
    __shared__ float Bs[BK][BN + 4];

    const int tiles_n = N / BN;
    const int by = blockIdx.x / tiles_n;
    const int bx = blockIdx.x % tiles_n;
    const int row0 = by * BM, col0 = bx * BN;
    const int tid = threadIdx.x;
    const int tx = tid & 15, ty = tid >> 4;

    float acc[8][8];
#pragma unroll
    for (int m = 0; m < 8; ++m)
#pragma unroll
        for (int n = 0; n < 8; ++n) acc[m][n] = 0.f;

    for (int k0 = 0; k0 < K; k0 += BK) {
#pragma unroll
        for (int l = 0; l < 2; ++l) {
            int f = tid + l * 256;
            int r = f >> 2, c4 = f & 3;
            float4 v = *reinterpret_cast<const float4*>(
                A + (size_t)(row0 + r) * K + k0 + c4 * 4);
            As[c4 * 4 + 0][r] = v.x;
            As[c4 * 4 + 1][r] = v.y;
            As[c4 * 4 + 2][r] = v.z;
            As[c4 * 4 + 3][r] = v.w;
        }
        if (TRANSB) {
#pragma unroll
            for (int l = 0; l < 2; ++l) {
                int f = tid + l * 256;
                int r = f >> 2, c4 = f & 3;
                float4 v = *reinterpret_cast<const float4*>(
                    B + (size_t)(col0 + r) * K + k0 + c4 * 4);
                Bs[c4 * 4 + 0][r] = v.x;
                Bs[c4 * 4 + 1][r] = v.y;
                Bs[c4 * 4 + 2][r] = v.z;
                Bs[c4 * 4 + 3][r] = v.w;
            }
        } else {
#pragma unroll
            for (int l = 0; l < 2; ++l) {
                int f = tid + l * 256;
                int kr = f >> 5, n4 = f & 31;
                *reinterpret_cast<float4*>(&Bs[kr][n4 * 4]) =
                    *reinterpret_cast<const float4*>(
                        B + (size_t)(k0 + kr) * N + col0 + n4 * 4);
            }
        }
        __syncthreads();

#pragma unroll
        for (int kk = 0; kk < BK; ++kk) {
            float a[8], b[8];
            *(float4*)&a[0] = *(const float4*)&As[kk][ty * 8];
            *(float4*)&a[4] = *(const float4*)&As[kk][ty * 8 + 4];
            *(float4*)&b[0] = *(const float4*)&Bs[kk][tx * 8];
            *(float4*)&b[4] = *(const float4*)&Bs[kk][tx * 8 + 4];
#pragma unroll
            for (int m = 0; m < 8; ++m)
#pragma unroll
                for (int n = 0; n < 8; ++n)
                    acc[m][n] = fmaf(a[m], b[n], acc[m][n]);
        }
        __syncthreads();
    }

    const int crow = row0 + ty * 8;
    const int ccol = col0 + tx * 8;
    float bv[8];
#pragma unroll
    for (int n = 0; n < 8; ++n) bv[n] = bias ? bias[ccol + n] : 0.f;
#pragma unroll
    for (int m = 0; m < 8; ++m) {
        float o[8];
#pragma unroll
        for (int n = 0; n < 8; ++n) {
            float t = acc[m][n] + bv[n];
            if (ACT == 1) t = fmaxf(t, 0.f);
            o[n] = t;
        }
        *reinterpret_cast<float4*>(C + (size_t)(crow + m) * N + ccol)     = *(float4*)&o[0];
        *reinterpret_cast<float4*>(C + (size_t)(crow + m) * N + ccol + 4) = *(float4*)&o[4];
    }
}

// ---------------------------------------------------------------------------
// Row L2-normalize + emit bf16 copy
// ---------------------------------------------------------------------------
__global__ __launch_bounds__(256)
void rownorm_emit_kernel(float* __restrict__ emb, unsigned short* __restrict__ ehi) {
    const int row = blockIdx.x, tid = threadIdx.x;
    float* rp = emb + (size_t)row * DD;
    float v0 = rp[tid], v1 = rp[tid + 256];
    float sum = v0 * v0 + v1 * v1;
#pragma unroll
    for (int off = 32; off > 0; off >>= 1) sum += __shfl_down(sum, off, 64);
    __shared__ float ws[4];
    __shared__ float sc_sh;
    if ((tid & 63) == 0) ws[tid >> 6] = sum;
    __syncthreads();
    if (tid == 0) {
        float n = sqrtf(ws[0] + ws[1] + ws[2] + ws[3]);
        sc_sh = 1.0f / fmaxf(n, 1e-12f);
    }
    __syncthreads();
    float sc = sc_sh;
    v0 *= sc; v1 *= sc;
    rp[tid] = v0;
    rp[tid + 256] = v1;
    ehi[(size_t)row * DD + tid]       = f2bf(v0);
    ehi[(size_t)row * DD + tid + 256] = f2bf(v1);
}

// ---------------------------------------------------------------------------
// Split fp32 -> (hi, lo) bf16 pair
// ---------------------------------------------------------------------------
__global__ __launch_bounds__(256)
void split_kernel(const float* __restrict__ e, unsigned short* __restrict__ hi,
                  unsigned short* __restrict__ lo) {
    const int i = (blockIdx.x * 256 + threadIdx.x) * 4;
    float4 v = *reinterpret_cast<const float4*>(e + i);
    ushort4 h, l;
    h.x = f2bf(v.x); l.x = f2bf(v.x - bf2f(h.x));
    h.y = f2bf(v.y); l.y = f2bf(v.y - bf2f(h.y));
    h.z = f2bf(v.z); l.z = f2bf(v.z - bf2f(h.z));
    h.w = f2bf(v.w); l.w = f2bf(v.w - bf2f(h.w));
    *reinterpret_cast<ushort4*>(hi + i) = h;
    *reinterpret_cast<ushort4*>(lo + i) = l;
}

// ---------------------------------------------------------------------------
// Transpose + split weights: W [K,N] fp32 -> Thi/Tlo [N,K] bf16
// ---------------------------------------------------------------------------
__global__ __launch_bounds__(256)
void wtrans_kernel(const float* __restrict__ W, unsigned short* __restrict__ Thi,
                   unsigned short* __restrict__ Tlo, int K, int N) {
    int t = blockIdx.x * 256 + threadIdx.x;
    if (t >= K * N) return;
    int k = t / N, n = t - k * N;
    float x = W[t];
    unsigned short h = f2bf(x);
    Thi[(size_t)n * K + k] = h;
    Tlo[(size_t)n * K + k] = f2bf(x - bf2f(h));
}

// ---------------------------------------------------------------------------
// approx sim = Ehi * Ehi^T (single bf16 MFMA product), output stored as bf16.
// ---------------------------------------------------------------------------
__global__ __launch_bounds__(256)
void simgemm_bf16(const unsigned short* __restrict__ Ehi,
                  unsigned short* __restrict__ Cb) {
    const int bid = blockIdx.x;
    const int swz = (bid & 7) * 512 + (bid >> 3);
    const int by = swz >> 6, bx = swz & 63;

    __shared__ unsigned short Ah[128 * 32];
    __shared__ unsigned short Bh[128 * 32];

    const int tid = threadIdx.x, lane = tid & 63, wid = tid >> 6;
    const int wm = wid >> 1, wn = wid & 1;
    const int fr = lane & 15, fq = lane >> 4;
    const int lrow = lane >> 2;
    const int lcol8 = (lane & 3) * 8;

    const size_t arow0 = (size_t)by * 128;
    const size_t brow0 = (size_t)bx * 128;

    f32x4 acc[4][4];
#pragma unroll
    for (int m = 0; m < 4; ++m)
#pragma unroll
        for (int n = 0; n < 4; ++n) acc[m][n] = (f32x4){0.f, 0.f, 0.f, 0.f};

    for (int k0 = 0; k0 < DD; k0 += 32) {
#pragma unroll
        for (int i = 0; i < 2; ++i) {
            const int chunk = wid + i * 4;
            const int grow = chunk * 16 + lrow;
            GLD16(Ehi + (arow0 + grow) * DD + (k0 + lcol8), Ah + chunk * 512);
            GLD16(Ehi + (brow0 + grow) * DD + (k0 + lcol8), Bh + chunk * 512);
        }
        __syncthreads();

        bf16x8 ah[4], bh[4];
#pragma unroll
        for (int mf = 0; mf < 4; ++mf)
            ah[mf] = *(const bf16x8*)&Ah[(wm * 64 + mf * 16 + fr) * 32 + fq * 8];
#pragma unroll
        for (int nf = 0; nf < 4; ++nf)
            bh[nf] = *(const bf16x8*)&Bh[(wn * 64 + nf * 16 + fr) * 32 + fq * 8];
#pragma unroll
        for (int mf = 0; mf < 4; ++mf)
#pragma unroll
            for (int nf = 0; nf < 4; ++nf)
                acc[mf][nf] = __builtin_amdgcn_mfma_f32_16x16x32_bf16(ah[mf], bh[nf], acc[mf][nf], 0, 0, 0);
        __syncthreads();
    }

#pragma unroll
    for (int mf = 0; mf < 4; ++mf) {
#pragma unroll
        for (int nf = 0; nf < 4; ++nf) {
            const size_t row = arow0 + wm * 64 + mf * 16 + fq * 4;
            const int col = bx * 128 + wn * 64 + nf * 16 + fr;
#pragma unroll
            for (int r2 = 0; r2 < 4; ++r2)
                Cb[(row + r2) * NN + col] = f2bf(acc[mf][nf][r2]);
        }
    }
}

// ---------------------------------------------------------------------------
// bf16x3 MFMA GEMM (NT) with bias: x1/x2 path
// ---------------------------------------------------------------------------
template<int KDIM>
__global__ __launch_bounds__(256)
void mfma_nt_bias(const unsigned short* __restrict__ Ahi,
                  const unsigned short* __restrict__ Alo,
                  const unsigned short* __restrict__ Bhi,
                  const unsigned short* __restrict__ Blo,
                  const float* __restrict__ bias, float* __restrict__ C, int N) {
    const int tiles_n = N / 128;
    const int by = blockIdx.x / tiles_n, bx = blockIdx.x % tiles_n;

    __shared__ unsigned short Ah[128 * 32];
    __shared__ unsigned short Al[128 * 32];
    __shared__ unsigned short Bh[128 * 32];
    __shared__ unsigned short Bl[128 * 32];

    const int tid = threadIdx.x, lane = tid & 63, wid = tid >> 6;
    const int wm = wid >> 1, wn = wid & 1;
    const int fr = lane & 15, fq = lane >> 4;
    const int lrow = lane >> 2;
    const int lcol8 = (lane & 3) * 8;

    const size_t arow0 = (size_t)by * 128;
    const size_t brow0 = (size_t)bx * 128;

    f32x4 acc[4][4];
#pragma unroll
    for (int m = 0; m < 4; ++m)
#pragma unroll
        for (int n = 0; n < 4; ++n) acc[m][n] = (f32x4){0.f, 0.f, 0.f, 0.f};

    for (int k0 = 0; k0 < KDIM; k0 += 32) {
#pragma unroll
        for (int i = 0; i < 2; ++i) {
            const int chunk = wid + i * 4;
            const int grow = chunk * 16 + lrow;
            GLD16(Ahi + (arow0 + grow) * KDIM + (k0 + lcol8), Ah + chunk * 512);
            GLD16(Alo + (arow0 + grow) * KDIM + (k0 + lcol8), Al + chunk * 512);
            GLD16(Bhi + (brow0 + grow) * KDIM + (k0 + lcol8), Bh + chunk * 512);
            GLD16(Blo + (brow0 + grow) * KDIM + (k0 + lcol8), Bl + chunk * 512);
        }
        __syncthreads();

        bf16x8 ah[4], al[4], bh[4], bl[4];
#pragma unroll
        for (int mf = 0; mf < 4; ++mf) {
            const int r = wm * 64 + mf * 16 + fr;
            ah[mf] = *(const bf16x8*)&Ah[r * 32 + fq * 8];
            al[mf] = *(const bf16x8*)&Al[r * 32 + fq * 8];
        }
#pragma unroll
        for (int nf = 0; nf < 4; ++nf) {
            const int r = wn * 64 + nf * 16 + fr;
            bh[nf] = *(const bf16x8*)&Bh[r * 32 + fq * 8];
            bl[nf] = *(const bf16x8*)&Bl[r * 32 + fq * 8];
        }
#pragma unroll
        for (int mf = 0; mf < 4; ++mf)
#pragma unroll
            for (int nf = 0; nf < 4; ++nf) {
                acc[mf][nf] = __builtin_amdgcn_mfma_f32_16x16x32_bf16(ah[mf], bh[nf], acc[mf][nf], 0, 0, 0);
                acc[mf][nf] = __builtin_amdgcn_mfma_f32_16x16x32_bf16(ah[mf], bl[nf], acc[mf][nf], 0, 0, 0);
                acc[mf][nf] = __builtin_amdgcn_mfma_f32_16x16x32_bf16(al[mf], bh[nf], acc[mf][nf], 0, 0, 0);
            }
        __syncthreads();
    }

#pragma unroll
    for (int mf = 0; mf < 4; ++mf) {
#pragma unroll
        for (int nf = 0; nf < 4; ++nf) {
            const size_t row = arow0 + wm * 64 + mf * 16 + fq * 4;
            const int col = bx * 128 + wn * 64 + nf * 16 + fr;
            const float bv = bias[col];
#pragma unroll
            for (int r2 = 0; r2 < 4; ++r2)
                C[(row + r2) * N + col] = acc[mf][nf][r2] + bv;
        }
    }
}

// ---------------------------------------------------------------------------
// FUSED: histogram candidate selection + exact fp32 refine + top-21 + edge push
// ---------------------------------------------------------------------------
__global__ __launch_bounds__(256)
void topk_refine_kernel(const unsigned short* __restrict__ simb,
                        const float* __restrict__ emb,
                        int* __restrict__ tidx, float* __restrict__ tval,
                        int* __restrict__ ecnt, int* __restrict__ elj,
                        float* __restrict__ elv) {
    const int row = blockIdx.x;
    const int tid = threadIdx.x;
    const int lane = tid & 63, wave = tid >> 6;

    // ---- phase 1: load row, histogram, threshold ----
    const uint4* rp = reinterpret_cast<const uint4*>(simb + (size_t)row * NN);
    uint4 q[4];
#pragma unroll
    for (int t = 0; t < 4; ++t) q[t] = rp[t * 256 + tid];
    unsigned pk[16];
#pragma unroll
    for (int t = 0; t < 4; ++t) {
        pk[t * 4 + 0] = q[t].x; pk[t * 4 + 1] = q[t].y;
        pk[t * 4 + 2] = q[t].z; pk[t * 4 + 3] = q[t].w;
    }

    __shared__ int hist[NBIN];
    for (int b = tid; b < NBIN; b += 256) hist[b] = 0;
    __syncthreads();

    short bins[32];
#pragma unroll
    for (int u = 0; u < 16; ++u) {
        float flo = __uint_as_float(pk[u] << 16);
        float fhi = __uint_as_float(pk[u] & 0xFFFF0000u);
        int blo = (int)(flo * (float)NBIN); blo = max(0, min(NBIN - 1, blo));
        int bhi = (int)(fhi * (float)NBIN); bhi = max(0, min(NBIN - 1, bhi));
        bins[u * 2]     = (short)blo;
        bins[u * 2 + 1] = (short)bhi;
        atomicAdd(&hist[blo], 1);
        atomicAdd(&hist[bhi], 1);
    }
    __syncthreads();

    __shared__ int s_bstar;
    if (wave == 0) {
        int cum = 0, found = -1;
        for (int c0 = NBIN - 1; c0 >= 0 && found < 0; c0 -= 64) {
            int b = c0 - lane;
            int cnt = (b >= 0) ? hist[b] : 0;
            int sc = cnt;
#pragma unroll
            for (int off = 1; off < 64; off <<= 1) {
                int o = __shfl_up(sc, off, 64);
                if (lane >= off) sc += o;
            }
            int chunk_total = __shfl(sc, 63, 64);
            bool hit = (cum + sc >= CMIN);
            unsigned long long mh = __ballot(hit);
            if (mh) found = c0 - (__ffsll((long long)mh) - 1);
            else cum += chunk_total;
        }
        if (found < 0) found = 0;
        if (lane == 0) s_bstar = found;
    }
    __syncthreads();
    const int bstar = s_bstar;

    // ---- phase 2: deterministic compaction of candidates into LDS ----
    __shared__ int s_cand[CCAP];
    int cnt = 0;
#pragma unroll
    for (int i = 0; i < 32; ++i) cnt += (bins[i] >= bstar) ? 1 : 0;
    int sc = cnt;
#pragma unroll
    for (int off = 1; off < 64; off <<= 1) {
        int o = __shfl_up(sc, off, 64);
        if (lane >= off) sc += o;
    }
    __shared__ int wtot[4];
    if (lane == 63) wtot[wave] = sc;
    __syncthreads();
    int base = sc - cnt;
#pragma unroll
    for (int w = 0; w < 4; ++w)
        if (w < wave) base += wtot[w];
    int total = wtot[0] + wtot[1] + wtot[2] + wtot[3];

    int pos = base;
#pragma unroll
    for (int u = 0; u < 16; ++u) {
#pragma unroll
        for (int h = 0; h < 2; ++h) {
            if (bins[u * 2 + h] >= bstar) {
                if (pos < CCAP)
                    s_cand[pos] = ((u >> 2) * 256 + tid) * 8 + (u & 3) * 2 + h;
                pos++;
            }
        }
    }
    __syncthreads();
    const int ncand = min(total, CCAP);

    // ---- phase 3: exact fp32 dots for candidates ----
    __shared__ float sval[CCAP];
    __shared__ int   sidx[CCAP];
    const float* ei = emb + (size_t)row * DD;
    float4 a0 = reinterpret_cast<const float4*>(ei)[lane * 2];
    float4 a1 = reinterpret_cast<const float4*>(ei)[lane * 2 + 1];

    for (int base2 = wave * 2; base2 < ncand; base2 += 8) {
#pragma unroll
        for (int qq = 0; qq < 2; ++qq) {
            int c = base2 + qq;
            if (c >= ncand) break;
            const int j = s_cand[c];
            const float* ej = emb + (size_t)j * DD;
            float4 b0 = reinterpret_cast<const float4*>(ej)[lane * 2];
            float4 b1 = reinterpret_cast<const float4*>(ej)[lane * 2 + 1];
            float s = 0.f;
            s = fmaf(a0.x, b0.x, s); s = fmaf(a0.y, b0.y, s);
            s = fmaf(a0.z, b0.z, s); s = fmaf(a0.w, b0.w, s);
            s = fmaf(a1.x, b1.x, s); s = fmaf(a1.y, b1.y, s);
            s = fmaf(a1.z, b1.z, s); s = fmaf(a1.w, b1.w, s);
#pragma unroll
            for (int off = 32; off > 0; off >>= 1) s += __shfl_xor(s, off, 64);
            if (lane == 0) { sval[c] = s; sidx[c] = j; }
        }
    }
    __syncthreads();

    // ---- phase 4: wave0 selects top-21 (value desc, idx asc) ----
    __shared__ float selv[KTOP];
    __shared__ int   seli[KTOP];
    if (wave == 0) {
        float v[3]; int id[3];
#pragma unroll
        for (int k = 0; k < 3; ++k) {
            int s = lane + 64 * k;
            if (s < ncand) { v[k] = sval[s]; id[k] = sidx[s]; }
            else           { v[k] = -INFINITY; id[k] = 0x7fffffff; }
        }
#pragma unroll 1
        for (int sel = 0; sel < KTOP; ++sel) {
            float bv = v[0]; int bi = id[0];
#pragma unroll
            for (int k = 1; k < 3; ++k)
                if (v[k] > bv || (v[k] == bv && id[k] < bi)) { bv = v[k]; bi = id[k]; }
#pragma unroll
            for (int off = 1; off < 64; off <<= 1) {
                float ov = __shfl_xor(bv, off, 64);
                int   oi = __shfl_xor(bi, off, 64);
                if (ov > bv || (ov == bv && oi < bi)) { bv = ov; bi = oi; }
            }
            if (lane == 0) { selv[sel] = bv; seli[sel] = bi; }
#pragma unroll
            for (int k = 0; k < 3; ++k)
                if (id[k] == bi) { v[k] = -INFINITY; id[k] = 0x7fffffff; }
        }
    }
    __syncthreads();

    // ---- phase 5: write topk + push edges into lists ----
    if (tid < KTOP) {
        float bv = selv[tid];
        int   bi = seli[tid];
        tval[(size_t)row * KTOP + tid] = bv;
        tidx[(size_t)row * KTOP + tid] = bi;
        if (bi != row && bi >= 0 && bi < NN && bv > 0.f) {
            float v = bv * 0.5f;
            int pi = atomicAdd(ecnt + row, 1);
            if (pi < ECAP) { elj[(size_t)row * ECAP + pi] = bi; elv[(size_t)row * ECAP + pi] = v; }
            int pj = atomicAdd(ecnt + bi, 1);
            if (pj < ECAP) { elj[(size_t)bi * ECAP + pj] = row; elv[(size_t)bi * ECAP + pj] = v; }
        }
    }
}

// ---------------------------------------------------------------------------
// Sort each row's edge list by (j, valbits) -> deterministic spmm order.
// ---------------------------------------------------------------------------
__global__ __launch_bounds__(256)
void sort_kernel(int* __restrict__ ej, float* __restrict__ ev,
                 const int* __restrict__ ecnt) {
    const int row = blockIdx.x, tid = threadIdx.x;
    const int nraw = ecnt[row];
    if (nraw > ECAP) return;  // overflow rows use dense fallback in spmm

    const int n = nraw;
    __shared__ int   lj[ECAP];
    __shared__ float lv[ECAP];
    __shared__ unsigned long long skey[ECAP];
    __shared__ int   oj[ECAP];
    __shared__ float ov[ECAP];
    if (tid < n) {
        int  jv = ej[(size_t)row * ECAP + tid];
        float vv = ev[(size_t)row * ECAP + tid];
        lj[tid] = jv; lv[tid] = vv;
        skey[tid] = ((unsigned long long)(unsigned)jv << 32) | (unsigned long long)ordkey(vv);
    }
    __syncthreads();
    if (tid < n) {
        unsigned long long mk = skey[tid];
        int rank = 0;
        for (int u = 0; u < n; ++u) {
            unsigned long long ku = skey[u];
            rank += (ku < mk || (ku == mk && u < tid)) ? 1 : 0;
        }
        oj[rank] = lj[tid];
        ov[rank] = lv[tid];
    }
    __syncthreads();
    if (tid < n) {
        ej[(size_t)row * ECAP + tid] = oj[tid];
        ev[(size_t)row * ECAP + tid] = ov[tid];
    }
}

// ---------------------------------------------------------------------------
// Paint: build dense adj row in LDS from edge list, stream out (coalesced),
// compute sdeg in the same pass. Each column gets <=2 contributions that are
// bitwise-equal => LDS atomic order is irrelevant => deterministic.
// Overflow rows rebuild from the full topk tables (rare, deterministic).
// ---------------------------------------------------------------------------
__global__ __launch_bounds__(256)
void paint_kernel(const int* __restrict__ ej, const float* __restrict__ ev,
                  const int* __restrict__ ecnt,
                  const int* __restrict__ tidx, const float* __restrict__ tval,
                  float* __restrict__ adj, float* __restrict__ sdeg) {
    const int row = blockIdx.x, tid = threadIdx.x;
    const int lane = tid & 63, wave = tid >> 6;
    __shared__ float rowbuf[NN];            // 32 KB
    for (int c = tid; c < NN; c += 256) rowbuf[c] = 0.f;
    __syncthreads();

    const int nraw = ecnt[row];
    if (nraw <= ECAP) {
        for (int e = tid; e < nraw; e += 256)
            atomicAdd(&rowbuf[ej[(size_t)row * ECAP + e]], ev[(size_t)row * ECAP + e]);
    } else {
        for (int t = tid; t < NN * KTOP; t += 256) {
            int i = t / KTOP;
            int j = tidx[t];
            float v = tval[t];
            if (j < 0 || j == i || v <= 0.f) continue;
            v *= 0.5f;
            if (i == row) atomicAdd(&rowbuf[j], v);
            if (j == row) atomicAdd(&rowbuf[i], v);
        }
    }
    __syncthreads();

    float sum = 0.f;
    float4* out4 = reinterpret_cast<float4*>(adj + (size_t)row * NN);
    const float4* rb4 = reinterpret_cast<const float4*>(rowbuf);
    for (int f = tid; f < NN / 4; f += 256) {
        float4 v = rb4[f];
        out4[f] = v;
        sum += (v.x + v.y) + (v.z + v.w);
    }
#pragma unroll
    for (int off = 32; off > 0; off >>= 1) sum += __shfl_down(sum, off, 64);
    __shared__ float ws[4];
    if (lane == 0) ws[wave] = sum;
    __syncthreads();
    if (tid == 0)
        sdeg[row] = 1.0f / (sqrtf(1.0f + ws[0] + ws[1] + ws[2] + ws[3]) + 1e-10f);
}

// ---------------------------------------------------------------------------
// SpMM from sorted edge lists (deterministic); dense-scan fallback on ovf.
// ---------------------------------------------------------------------------
template<int COLS, bool DORELU>
__global__ __launch_bounds__(256)
void spmm_edges(const int* __restrict__ ej, const float* __restrict__ ev,
                const int* __restrict__ ecnt, const float* __restrict__ adj,
                const float* __restrict__ sdeg,
                const float* __restrict__ X, float* __restrict__ Y) {
    constexpr int CPT = COLS / 256;
    const int i = blockIdx.x;
    const int tid = threadIdx.x;
    const int lane = tid & 63, wave = tid >> 6;
    const float si = sdeg[i];
    const int nraw = ecnt[i];

    float acc[CPT];
#pragma unroll
    for (int c = 0; c < CPT; ++c) acc[c] = 0.f;

    if (nraw <= ECAP) {
        __shared__ int   s_j[ECAP];
        __shared__ float s_w[ECAP];
        if (tid < nraw) {
            int j = ej[(size_t)i * ECAP + tid];
            s_j[tid] = j;
            s_w[tid] = ev[(size_t)i * ECAP + tid] * sdeg[j];
        }
        __syncthreads();
#pragma unroll 4
        for (int e = 0; e < nraw; ++e) {
            int j = s_j[e];
            float we = s_w[e];
#pragma unroll
            for (int c = 0; c < CPT; ++c)
                acc[c] += we * X[(size_t)j * COLS + tid + c * 256];
        }
    } else {
        __shared__ int   s_j[256];
        __shared__ float s_w[256];
        __shared__ int   s_cnt[4];
        const float* rowp = adj + (size_t)i * NN;
        for (int j0 = 0; j0 < NN; j0 += 256) {
            float w = rowp[j0 + tid];
            bool nz = (w != 0.f);
            unsigned long long m = __ballot(nz);
            unsigned long long ltmask = (lane == 0) ? 0ull : (~0ull >> (64 - lane));
            int pre = __popcll(m & ltmask);
            if (lane == 0) s_cnt[wave] = __popcll(m);
            __syncthreads();
            int base = 0;
#pragma unroll
            for (int q = 0; q < 4; ++q)
                if (q < wave) base += s_cnt[q];
            int total = s_cnt[0] + s_cnt[1] + s_cnt[2] + s_cnt[3];
            if (nz) {
                int p = base + pre;
                s_j[p] = j0 + tid;
                s_w[p] = w * sdeg[j0 + tid];
            }
            __syncthreads();
            for (int e = 0; e < total; ++e) {
                int j = s_j[e];
                float we = s_w[e];
#pragma unroll
                for (int c = 0; c < CPT; ++c)
                    acc[c] += we * X[(size_t)j * COLS + tid + c * 256];
            }
            __syncthreads();
        }
    }

#pragma unroll
    for (int c = 0; c < CPT; ++c) {
        float val = si * (acc[c] + si * X[(size_t)i * COLS + tid + c * 256]);
        if (DORELU) val = fmaxf(val, 0.f);
        Y[(size_t)i * COLS + tid + c * 256] = val;
    }
}

// ---------------------------------------------------------------------------
extern "C" void kernel_launch(void* const* d_in, const int* in_sizes, int n_in,
                              void* d_out, int out_size, void* d_ws, size_t ws_size,
                              hipStream_t stream) {
    const float* features = (const float*)d_in[0];
    const float* masked   = (const float*)d_in[1];
    const float* W1  = (const float*)d_in[2];
    const float* b1  = (const float*)d_in[3];
    const float* W2  = (const float*)d_in[4];
    const float* b2  = (const float*)d_in[5];
    const float* Wg1 = (const float*)d_in[6];
    const float* bg1 = (const float*)d_in[7];
    const float* Wg2 = (const float*)d_in[8];
    const float* bg2 = (const float*)d_in[9];

    float* out_h3  = (float*)d_out;                      // [NN, DD]
    float* out_adj = (float*)d_out + (size_t)NN * DD;    // [NN, NN] (bf16 sim scratch too)
    unsigned short* simb = (unsigned short*)out_adj;     // bf16 sim view

    float* Areg = (float*)d_ws;
    float* Breg = Areg + (size_t)NN * DD;
    float* tail = Breg + (size_t)NN * DD;

    float* h    = Areg;
    unsigned short* ehi = (unsigned short*)Areg;          // NN*DD bf16
    unsigned short* mhi = (unsigned short*)Areg;          // NN*DD bf16
    unsigned short* mlo = mhi + (size_t)NN * DD;
    unsigned short* h1hi = (unsigned short*)Areg;         // NN*HH bf16
    unsigned short* h1lo = h1hi + (size_t)NN * HH;

    float* emb = Breg;
    float* x1  = Breg;                                    // [NN,HH] fp32
    float* h1  = Breg + (size_t)NN * HH;                  // [NN,HH] fp32
    float* x2  = Breg;                                    // [NN,DD] fp32

    float* tval = tail;                                   // NN*KTOP
    int*   tidx = (int*)(tval + (size_t)NN * KTOP);       // NN*KTOP
    float* sdeg = (float*)(tidx + (size_t)NN * KTOP);     // NN
    int*   ecnt = (int*)(sdeg + NN);                      // NN
    int*   elj  = ecnt + NN;                              // NN*ECAP
    float* elv  = (float*)(elj + (size_t)NN * ECAP);      // NN*ECAP
    unsigned short* wt1hi = (unsigned short*)(elv + (size_t)NN * ECAP); // HH*DD
    unsigned short* wt1lo = wt1hi + (size_t)HH * DD;
    unsigned short* wt2hi = wt1lo + (size_t)HH * DD;      // DD*HH
    unsigned short* wt2lo = wt2hi + (size_t)DD * HH;

    dim3 blk(256);

    // 1-2) MLP (fp32 — selection accuracy depends on emb)
    sgemm128<false, 1><<<dim3((NN / 128) * (DD / 128)), blk, 0, stream>>>(
        features, W1, b1, h, NN, DD, DD);
    sgemm128<false, 0><<<dim3((NN / 128) * (DD / 128)), blk, 0, stream>>>(
        h, W2, b2, emb, NN, DD, DD);
    // 3) normalize + emit bf16 (h dead -> ehi overlays it)
    rownorm_emit_kernel<<<dim3(NN), blk, 0, stream>>>(emb, ehi);
    // 4) approx sim (bf16 in/out) -> out_adj scratch
    simgemm_bf16<<<dim3(4096), blk, 0, stream>>>(ehi, simb);
    // 5) clear edge counters, then fused candidate-select + refine + edge push
    hipMemsetAsync(ecnt, 0, (size_t)NN * sizeof(int), stream);
    topk_refine_kernel<<<dim3(NN), blk, 0, stream>>>(
        simb, emb, tidx, tval, ecnt, elj, elv);
    // 6) sort edge lists (deterministic spmm order)
    sort_kernel<<<dim3(NN), blk, 0, stream>>>(elj, elv, ecnt);
    // 7) paint dense adjacency + degrees (replaces zero + dense scatter + deg)
    paint_kernel<<<dim3(NN), blk, 0, stream>>>(
        elj, elv, ecnt, tidx, tval, out_adj, sdeg);
    // 8-10) x1 = masked @ Wg1 + bg1 via bf16x3 MFMA
    split_kernel<<<dim3(NN * DD / 1024), blk, 0, stream>>>(masked, mhi, mlo);
    wtrans_kernel<<<dim3(DD * HH / 256), blk, 0, stream>>>(Wg1, wt1hi, wt1lo, DD, HH);
    mfma_nt_bias<DD><<<dim3((NN / 128) * (HH / 128)), blk, 0, stream>>>(
        mhi, mlo, wt1hi, wt1lo, bg1, x1, HH);
    // 11) h1 = relu(Ahat @ x1)
    spmm_edges<HH, true><<<dim3(NN), blk, 0, stream>>>(
        elj, elv, ecnt, out_adj, sdeg, x1, h1);
    // 12-14) x2 = h1 @ Wg2 + bg2 via bf16x3 MFMA
    split_kernel<<<dim3(NN * HH / 1024), blk, 0, stream>>>(h1, h1hi, h1lo);
    wtrans_kernel<<<dim3(HH * DD / 256), blk, 0, stream>>>(Wg2, wt2hi, wt2lo, HH, DD);
    mfma_nt_bias<HH><<<dim3((NN / 128) * (DD / 128)), blk, 0, stream>>>(
        h1hi, h1lo, wt2hi, wt2lo, bg2, x2, DD);
    // 15) h3 = Ahat @ x2 -> d_out
    spmm_edges<DD, false><<<dim3(NN), blk, 0, stream>>>(
        elj, elv, ecnt, out_adj, sdeg, x2, out_h3);
}

// Round 7
// 745.192 us; speedup vs baseline: 1.4258x; 1.4258x over previous
//
#include <hip/hip_runtime.h>
#include <cstdint>
#include <cstddef>

#define NN 8192
#define DD 512
#define HH 256
#define KTOP 21
#define CCAP 192   // candidate collection capacity
#define CMIN 48    // minimum candidates (superset of top-21 w/ bf16 margin)
#define ECAP 224   // per-row edge-list capacity
#define NBIN 1024

typedef __attribute__((ext_vector_type(8))) __bf16 bf16x8;
typedef __attribute__((ext_vector_type(4))) float f32x4;

__device__ __forceinline__ unsigned short f2bf(float x) {
    unsigned u = __float_as_uint(x);
    u += 0x7fffu + ((u >> 16) & 1u);
    return (unsigned short)(u >> 16);
}
__device__ __forceinline__ float bf2f(unsigned short h) {
    return __uint_as_float(((unsigned)h) << 16);
}
// order-preserving key: monotone map float -> uint (used by sortdeg)
__device__ __forceinline__ unsigned ordkey(float x) {
    unsigned b = __float_as_uint(x);
    return b ^ (((int)b >> 31) | 0x80000000u);
}

#define GLD16(gp, lp) __builtin_amdgcn_global_load_lds( \
    (const __attribute__((address_space(1))) unsigned int*)(gp), \
    (__attribute__((address_space(3))) unsigned int*)(lp), 16, 0, 0)

// ---------------------------------------------------------------------------
// fp32 SGEMM: GEMM1/2 (emb path must stay fp32-exact for selection)
// ---------------------------------------------------------------------------
template<bool TRANSB, int ACT>
__global__ __launch_bounds__(256)
void sgemm128(const float* __restrict__ A, const float* __restrict__ B,
              const float* __restrict__ bias, float* __restrict__ C,
              int M, int N, int K) {
    constexpr int BM = 128, BN = 128, BK = 16;
    __shared__ float As[BK][BM + 4];
    __shared__ float Bs[BK][BN + 4];

    const int tiles_n = N / BN;
    const int by = blockIdx.x / tiles_n;
    const int bx = blockIdx.x % tiles_n;
    const int row0 = by * BM, col0 = bx * BN;
    const int tid = threadIdx.x;
    const int tx = tid & 15, ty = tid >> 4;

    float acc[8][8];
#pragma unroll
    for (int m = 0; m < 8; ++m)
#pragma unroll
        for (int n = 0; n < 8; ++n) acc[m][n] = 0.f;

    for (int k0 = 0; k0 < K; k0 += BK) {
#pragma unroll
        for (int l = 0; l < 2; ++l) {
            int f = tid + l * 256;
            int r = f >> 2, c4 = f & 3;
            float4 v = *reinterpret_cast<const float4*>(
                A + (size_t)(row0 + r) * K + k0 + c4 * 4);
            As[c4 * 4 + 0][r] = v.x;
            As[c4 * 4 + 1][r] = v.y;
            As[c4 * 4 + 2][r] = v.z;
            As[c4 * 4 + 3][r] = v.w;
        }
        if (TRANSB) {
#pragma unroll
            for (int l = 0; l < 2; ++l) {
                int f = tid + l * 256;
                int r = f >> 2, c4 = f & 3;
                float4 v = *reinterpret_cast<const float4*>(
                    B + (size_t)(col0 + r) * K + k0 + c4 * 4);
                Bs[c4 * 4 + 0][r] = v.x;
                Bs[c4 * 4 + 1][r] = v.y;
                Bs[c4 * 4 + 2][r] = v.z;
                Bs[c4 * 4 + 3][r] = v.w;
            }
        } else {
#pragma unroll
            for (int l = 0; l < 2; ++l) {
                int f = tid + l * 256;
                int kr = f >> 5, n4 = f & 31;
                *reinterpret_cast<float4*>(&Bs[kr][n4 * 4]) =
                    *reinterpret_cast<const float4*>(
                        B + (size_t)(k0 + kr) * N + col0 + n4 * 4);
            }
        }
        __syncthreads();

#pragma unroll
        for (int kk = 0; kk < BK; ++kk) {
            float a[8], b[8];
            *(float4*)&a[0] = *(const float4*)&As[kk][ty * 8];
            *(float4*)&a[4] = *(const float4*)&As[kk][ty * 8 + 4];
            *(float4*)&b[0] = *(const float4*)&Bs[kk][tx * 8];
            *(float4*)&b[4] = *(const float4*)&Bs[kk][tx * 8 + 4];
#pragma unroll
            for (int m = 0; m < 8; ++m)
#pragma unroll
                for (int n = 0; n < 8; ++n)
                    acc[m][n] = fmaf(a[m], b[n], acc[m][n]);
        }
        __syncthreads();
    }

    const int crow = row0 + ty * 8;
    const int ccol = col0 + tx * 8;
    float bv[8];
#pragma unroll
    for (int n = 0; n < 8; ++n) bv[n] = bias ? bias[ccol + n] : 0.f;
#pragma unroll
    for (int m = 0; m < 8; ++m) {
        float o[8];
#pragma unroll
        for (int n = 0; n < 8; ++n) {
            float t = acc[m][n] + bv[n];
            if (ACT == 1) t = fmaxf(t, 0.f);
            o[n] = t;
        }
        *reinterpret_cast<float4*>(C + (size_t)(crow + m) * N + ccol)     = *(float4*)&o[0];
        *reinterpret_cast<float4*>(C + (size_t)(crow + m) * N + ccol + 4) = *(float4*)&o[4];
    }
}

// ---------------------------------------------------------------------------
// Row L2-normalize + emit bf16 copy
// ---------------------------------------------------------------------------
__global__ __launch_bounds__(256)
void rownorm_emit_kernel(float* __restrict__ emb, unsigned short* __restrict__ ehi) {
    const int row = blockIdx.x, tid = threadIdx.x;
    float* rp = emb + (size_t)row * DD;
    float v0 = rp[tid], v1 = rp[tid + 256];
    float sum = v0 * v0 + v1 * v1;
#pragma unroll
    for (int off = 32; off > 0; off >>= 1) sum += __shfl_down(sum, off, 64);
    __shared__ float ws[4];
    __shared__ float sc_sh;
    if ((tid & 63) == 0) ws[tid >> 6] = sum;
    __syncthreads();
    if (tid == 0) {
        float n = sqrtf(ws[0] + ws[1] + ws[2] + ws[3]);
        sc_sh = 1.0f / fmaxf(n, 1e-12f);
    }
    __syncthreads();
    float sc = sc_sh;
    v0 *= sc; v1 *= sc;
    rp[tid] = v0;
    rp[tid + 256] = v1;
    ehi[(size_t)row * DD + tid]       = f2bf(v0);
    ehi[(size_t)row * DD + tid + 256] = f2bf(v1);
}

// ---------------------------------------------------------------------------
// Split fp32 -> (hi, lo) bf16 pair
// ---------------------------------------------------------------------------
__global__ __launch_bounds__(256)
void split_kernel(const float* __restrict__ e, unsigned short* __restrict__ hi,
                  unsigned short* __restrict__ lo) {
    const int i = (blockIdx.x * 256 + threadIdx.x) * 4;
    float4 v = *reinterpret_cast<const float4*>(e + i);
    ushort4 h, l;
    h.x = f2bf(v.x); l.x = f2bf(v.x - bf2f(h.x));
    h.y = f2bf(v.y); l.y = f2bf(v.y - bf2f(h.y));
    h.z = f2bf(v.z); l.z = f2bf(v.z - bf2f(h.z));
    h.w = f2bf(v.w); l.w = f2bf(v.w - bf2f(h.w));
    *reinterpret_cast<ushort4*>(hi + i) = h;
    *reinterpret_cast<ushort4*>(lo + i) = l;
}

// ---------------------------------------------------------------------------
// Transpose + split weights: W [K,N] fp32 -> Thi/Tlo [N,K] bf16
// ---------------------------------------------------------------------------
__global__ __launch_bounds__(256)
void wtrans_kernel(const float* __restrict__ W, unsigned short* __restrict__ Thi,
                   unsigned short* __restrict__ Tlo, int K, int N) {
    int t = blockIdx.x * 256 + threadIdx.x;
    if (t >= K * N) return;
    int k = t / N, n = t - k * N;
    float x = W[t];
    unsigned short h = f2bf(x);
    Thi[(size_t)n * K + k] = h;
    Tlo[(size_t)n * K + k] = f2bf(x - bf2f(h));
}

// ---------------------------------------------------------------------------
// Zero the dense adjacency (grid-stride float4 — proven high-BW pattern)
// ---------------------------------------------------------------------------
__global__ __launch_bounds__(256)
void zero_kernel(float4* __restrict__ adj4) {
    const float4 z = {0.f, 0.f, 0.f, 0.f};
    size_t gid = (size_t)blockIdx.x * 256 + threadIdx.x;
    const size_t stride = (size_t)gridDim.x * 256;
    const size_t total = (size_t)NN * NN / 4;
    for (size_t i = gid; i < total; i += stride) adj4[i] = z;
}

// ---------------------------------------------------------------------------
// approx sim = Ehi * Ehi^T (single bf16 MFMA product), output stored as bf16.
// ---------------------------------------------------------------------------
__global__ __launch_bounds__(256)
void simgemm_bf16(const unsigned short* __restrict__ Ehi,
                  unsigned short* __restrict__ Cb) {
    const int bid = blockIdx.x;
    const int swz = (bid & 7) * 512 + (bid >> 3);
    const int by = swz >> 6, bx = swz & 63;

    __shared__ unsigned short Ah[128 * 32];
    __shared__ unsigned short Bh[128 * 32];

    const int tid = threadIdx.x, lane = tid & 63, wid = tid >> 6;
    const int wm = wid >> 1, wn = wid & 1;
    const int fr = lane & 15, fq = lane >> 4;
    const int lrow = lane >> 2;
    const int lcol8 = (lane & 3) * 8;

    const size_t arow0 = (size_t)by * 128;
    const size_t brow0 = (size_t)bx * 128;

    f32x4 acc[4][4];
#pragma unroll
    for (int m = 0; m < 4; ++m)
#pragma unroll
        for (int n = 0; n < 4; ++n) acc[m][n] = (f32x4){0.f, 0.f, 0.f, 0.f};

    for (int k0 = 0; k0 < DD; k0 += 32) {
#pragma unroll
        for (int i = 0; i < 2; ++i) {
            const int chunk = wid + i * 4;
            const int grow = chunk * 16 + lrow;
            GLD16(Ehi + (arow0 + grow) * DD + (k0 + lcol8), Ah + chunk * 512);
            GLD16(Ehi + (brow0 + grow) * DD + (k0 + lcol8), Bh + chunk * 512);
        }
        __syncthreads();

        bf16x8 ah[4], bh[4];
#pragma unroll
        for (int mf = 0; mf < 4; ++mf)
            ah[mf] = *(const bf16x8*)&Ah[(wm * 64 + mf * 16 + fr) * 32 + fq * 8];
#pragma unroll
        for (int nf = 0; nf < 4; ++nf)
            bh[nf] = *(const bf16x8*)&Bh[(wn * 64 + nf * 16 + fr) * 32 + fq * 8];
#pragma unroll
        for (int mf = 0; mf < 4; ++mf)
#pragma unroll
            for (int nf = 0; nf < 4; ++nf)
                acc[mf][nf] = __builtin_amdgcn_mfma_f32_16x16x32_bf16(ah[mf], bh[nf], acc[mf][nf], 0, 0, 0);
        __syncthreads();
    }

#pragma unroll
    for (int mf = 0; mf < 4; ++mf) {
#pragma unroll
        for (int nf = 0; nf < 4; ++nf) {
            const size_t row = arow0 + wm * 64 + mf * 16 + fq * 4;
            const int col = bx * 128 + wn * 64 + nf * 16 + fr;
#pragma unroll
            for (int r2 = 0; r2 < 4; ++r2)
                Cb[(row + r2) * NN + col] = f2bf(acc[mf][nf][r2]);
        }
    }
}

// ---------------------------------------------------------------------------
// bf16x3 MFMA GEMM (NT) with bias: x1/x2 path
// ---------------------------------------------------------------------------
template<int KDIM>
__global__ __launch_bounds__(256)
void mfma_nt_bias(const unsigned short* __restrict__ Ahi,
                  const unsigned short* __restrict__ Alo,
                  const unsigned short* __restrict__ Bhi,
                  const unsigned short* __restrict__ Blo,
                  const float* __restrict__ bias, float* __restrict__ C, int N) {
    const int tiles_n = N / 128;
    const int by = blockIdx.x / tiles_n, bx = blockIdx.x % tiles_n;

    __shared__ unsigned short Ah[128 * 32];
    __shared__ unsigned short Al[128 * 32];
    __shared__ unsigned short Bh[128 * 32];
    __shared__ unsigned short Bl[128 * 32];

    const int tid = threadIdx.x, lane = tid & 63, wid = tid >> 6;
    const int wm = wid >> 1, wn = wid & 1;
    const int fr = lane & 15, fq = lane >> 4;
    const int lrow = lane >> 2;
    const int lcol8 = (lane & 3) * 8;

    const size_t arow0 = (size_t)by * 128;
    const size_t brow0 = (size_t)bx * 128;

    f32x4 acc[4][4];
#pragma unroll
    for (int m = 0; m < 4; ++m)
#pragma unroll
        for (int n = 0; n < 4; ++n) acc[m][n] = (f32x4){0.f, 0.f, 0.f, 0.f};

    for (int k0 = 0; k0 < KDIM; k0 += 32) {
#pragma unroll
        for (int i = 0; i < 2; ++i) {
            const int chunk = wid + i * 4;
            const int grow = chunk * 16 + lrow;
            GLD16(Ahi + (arow0 + grow) * KDIM + (k0 + lcol8), Ah + chunk * 512);
            GLD16(Alo + (arow0 + grow) * KDIM + (k0 + lcol8), Al + chunk * 512);
            GLD16(Bhi + (brow0 + grow) * KDIM + (k0 + lcol8), Bh + chunk * 512);
            GLD16(Blo + (brow0 + grow) * KDIM + (k0 + lcol8), Bl + chunk * 512);
        }
        __syncthreads();

        bf16x8 ah[4], al[4], bh[4], bl[4];
#pragma unroll
        for (int mf = 0; mf < 4; ++mf) {
            const int r = wm * 64 + mf * 16 + fr;
            ah[mf] = *(const bf16x8*)&Ah[r * 32 + fq * 8];
            al[mf] = *(const bf16x8*)&Al[r * 32 + fq * 8];
        }
#pragma unroll
        for (int nf = 0; nf < 4; ++nf) {
            const int r = wn * 64 + nf * 16 + fr;
            bh[nf] = *(const bf16x8*)&Bh[r * 32 + fq * 8];
            bl[nf] = *(const bf16x8*)&Bl[r * 32 + fq * 8];
        }
#pragma unroll
        for (int mf = 0; mf < 4; ++mf)
#pragma unroll
            for (int nf = 0; nf < 4; ++nf) {
                acc[mf][nf] = __builtin_amdgcn_mfma_f32_16x16x32_bf16(ah[mf], bh[nf], acc[mf][nf], 0, 0, 0);
                acc[mf][nf] = __builtin_amdgcn_mfma_f32_16x16x32_bf16(ah[mf], bl[nf], acc[mf][nf], 0, 0, 0);
                acc[mf][nf] = __builtin_amdgcn_mfma_f32_16x16x32_bf16(al[mf], bh[nf], acc[mf][nf], 0, 0, 0);
            }
        __syncthreads();
    }

#pragma unroll
    for (int mf = 0; mf < 4; ++mf) {
#pragma unroll
        for (int nf = 0; nf < 4; ++nf) {
            const size_t row = arow0 + wm * 64 + mf * 16 + fq * 4;
            const int col = bx * 128 + wn * 64 + nf * 16 + fr;
            const float bv = bias[col];
#pragma unroll
            for (int r2 = 0; r2 < 4; ++r2)
                C[(row + r2) * N + col] = acc[mf][nf][r2] + bv;
        }
    }
}

// ---------------------------------------------------------------------------
// FUSED: histogram candidate selection + exact fp32 refine + top-21 + edge push
// ---------------------------------------------------------------------------
__global__ __launch_bounds__(256)
void topk_refine_kernel(const unsigned short* __restrict__ simb,
                        const float* __restrict__ emb,
                        int* __restrict__ tidx, float* __restrict__ tval,
                        int* __restrict__ ecnt, int* __restrict__ elj,
                        float* __restrict__ elv) {
    const int row = blockIdx.x;
    const int tid = threadIdx.x;
    const int lane = tid & 63, wave = tid >> 6;

    // ---- phase 1: load row, histogram, threshold ----
    const uint4* rp = reinterpret_cast<const uint4*>(simb + (size_t)row * NN);
    uint4 q[4];
#pragma unroll
    for (int t = 0; t < 4; ++t) q[t] = rp[t * 256 + tid];
    unsigned pk[16];
#pragma unroll
    for (int t = 0; t < 4; ++t) {
        pk[t * 4 + 0] = q[t].x; pk[t * 4 + 1] = q[t].y;
        pk[t * 4 + 2] = q[t].z; pk[t * 4 + 3] = q[t].w;
    }

    __shared__ int hist[NBIN];
    for (int b = tid; b < NBIN; b += 256) hist[b] = 0;
    __syncthreads();

    short bins[32];
#pragma unroll
    for (int u = 0; u < 16; ++u) {
        float flo = __uint_as_float(pk[u] << 16);
        float fhi = __uint_as_float(pk[u] & 0xFFFF0000u);
        int blo = (int)(flo * (float)NBIN); blo = max(0, min(NBIN - 1, blo));
        int bhi = (int)(fhi * (float)NBIN); bhi = max(0, min(NBIN - 1, bhi));
        bins[u * 2]     = (short)blo;
        bins[u * 2 + 1] = (short)bhi;
        atomicAdd(&hist[blo], 1);
        atomicAdd(&hist[bhi], 1);
    }
    __syncthreads();

    __shared__ int s_bstar;
    if (wave == 0) {
        int cum = 0, found = -1;
        for (int c0 = NBIN - 1; c0 >= 0 && found < 0; c0 -= 64) {
            int b = c0 - lane;
            int cnt = (b >= 0) ? hist[b] : 0;
            int sc = cnt;
#pragma unroll
            for (int off = 1; off < 64; off <<= 1) {
                int o = __shfl_up(sc, off, 64);
                if (lane >= off) sc += o;
            }
            int chunk_total = __shfl(sc, 63, 64);
            bool hit = (cum + sc >= CMIN);
            unsigned long long mh = __ballot(hit);
            if (mh) found = c0 - (__ffsll((long long)mh) - 1);
            else cum += chunk_total;
        }
        if (found < 0) found = 0;
        if (lane == 0) s_bstar = found;
    }
    __syncthreads();
    const int bstar = s_bstar;

    // ---- phase 2: deterministic compaction of candidates into LDS ----
    __shared__ int s_cand[CCAP];
    int cnt = 0;
#pragma unroll
    for (int i = 0; i < 32; ++i) cnt += (bins[i] >= bstar) ? 1 : 0;
    int sc = cnt;
#pragma unroll
    for (int off = 1; off < 64; off <<= 1) {
        int o = __shfl_up(sc, off, 64);
        if (lane >= off) sc += o;
    }
    __shared__ int wtot[4];
    if (lane == 63) wtot[wave] = sc;
    __syncthreads();
    int base = sc - cnt;
#pragma unroll
    for (int w = 0; w < 4; ++w)
        if (w < wave) base += wtot[w];
    int total = wtot[0] + wtot[1] + wtot[2] + wtot[3];

    int pos = base;
#pragma unroll
    for (int u = 0; u < 16; ++u) {
#pragma unroll
        for (int h = 0; h < 2; ++h) {
            if (bins[u * 2 + h] >= bstar) {
                if (pos < CCAP)
                    s_cand[pos] = ((u >> 2) * 256 + tid) * 8 + (u & 3) * 2 + h;
                pos++;
            }
        }
    }
    __syncthreads();
    const int ncand = min(total, CCAP);

    // ---- phase 3: exact fp32 dots for candidates ----
    __shared__ float sval[CCAP];
    __shared__ int   sidx[CCAP];
    const float* ei = emb + (size_t)row * DD;
    float4 a0 = reinterpret_cast<const float4*>(ei)[lane * 2];
    float4 a1 = reinterpret_cast<const float4*>(ei)[lane * 2 + 1];

    for (int base2 = wave * 2; base2 < ncand; base2 += 8) {
#pragma unroll
        for (int qq = 0; qq < 2; ++qq) {
            int c = base2 + qq;
            if (c >= ncand) break;
            const int j = s_cand[c];
            const float* ej = emb + (size_t)j * DD;
            float4 b0 = reinterpret_cast<const float4*>(ej)[lane * 2];
            float4 b1 = reinterpret_cast<const float4*>(ej)[lane * 2 + 1];
            float s = 0.f;
            s = fmaf(a0.x, b0.x, s); s = fmaf(a0.y, b0.y, s);
            s = fmaf(a0.z, b0.z, s); s = fmaf(a0.w, b0.w, s);
            s = fmaf(a1.x, b1.x, s); s = fmaf(a1.y, b1.y, s);
            s = fmaf(a1.z, b1.z, s); s = fmaf(a1.w, b1.w, s);
#pragma unroll
            for (int off = 32; off > 0; off >>= 1) s += __shfl_xor(s, off, 64);
            if (lane == 0) { sval[c] = s; sidx[c] = j; }
        }
    }
    __syncthreads();

    // ---- phase 4: wave0 selects top-21 (value desc, idx asc) ----
    __shared__ float selv[KTOP];
    __shared__ int   seli[KTOP];
    if (wave == 0) {
        float v[3]; int id[3];
#pragma unroll
        for (int k = 0; k < 3; ++k) {
            int s = lane + 64 * k;
            if (s < ncand) { v[k] = sval[s]; id[k] = sidx[s]; }
            else           { v[k] = -INFINITY; id[k] = 0x7fffffff; }
        }
#pragma unroll 1
        for (int sel = 0; sel < KTOP; ++sel) {
            float bv = v[0]; int bi = id[0];
#pragma unroll
            for (int k = 1; k < 3; ++k)
                if (v[k] > bv || (v[k] == bv && id[k] < bi)) { bv = v[k]; bi = id[k]; }
#pragma unroll
            for (int off = 1; off < 64; off <<= 1) {
                float ov = __shfl_xor(bv, off, 64);
                int   oi = __shfl_xor(bi, off, 64);
                if (ov > bv || (ov == bv && oi < bi)) { bv = ov; bi = oi; }
            }
            if (lane == 0) { selv[sel] = bv; seli[sel] = bi; }
#pragma unroll
            for (int k = 0; k < 3; ++k)
                if (id[k] == bi) { v[k] = -INFINITY; id[k] = 0x7fffffff; }
        }
    }
    __syncthreads();

    // ---- phase 5: write topk + push edges into lists ----
    if (tid < KTOP) {
        float bv = selv[tid];
        int   bi = seli[tid];
        tval[(size_t)row * KTOP + tid] = bv;
        tidx[(size_t)row * KTOP + tid] = bi;
        if (bi != row && bi >= 0 && bi < NN && bv > 0.f) {
            float v = bv * 0.5f;
            int pi = atomicAdd(ecnt + row, 1);
            if (pi < ECAP) { elj[(size_t)row * ECAP + pi] = bi; elv[(size_t)row * ECAP + pi] = v; }
            int pj = atomicAdd(ecnt + bi, 1);
            if (pj < ECAP) { elj[(size_t)bi * ECAP + pj] = row; elv[(size_t)bi * ECAP + pj] = v; }
        }
    }
}

// ---------------------------------------------------------------------------
// Dense scatter: adj[i,j] += 0.5*relu(topk) both directions (bitwise-equal
// halves => atomic order irrelevant => deterministic).
// ---------------------------------------------------------------------------
__global__ __launch_bounds__(256)
void scatter_dense(const int* __restrict__ tidx, const float* __restrict__ tval,
                   float* __restrict__ adj) {
    int t = blockIdx.x * 256 + threadIdx.x;
    if (t >= NN * KTOP) return;
    int i = t / KTOP;
    int j = tidx[t];
    if (j == i || j < 0) return;
    float v = tval[t];
    if (v <= 0.f) return;
    v *= 0.5f;
    atomicAdd(adj + (size_t)i * NN + j, v);
    atomicAdd(adj + (size_t)j * NN + i, v);
}

// ---------------------------------------------------------------------------
// Sort each row's edge list by (j, valbits); compute sdeg (deterministic).
// Overflow rows: dense scan of the final adj row (cheap, deterministic).
// ---------------------------------------------------------------------------
__global__ __launch_bounds__(256)
void sortdeg_kernel(int* __restrict__ ej, float* __restrict__ ev,
                    const int* __restrict__ ecnt, const float* __restrict__ adj,
                    float* __restrict__ sdeg) {
    const int row = blockIdx.x, tid = threadIdx.x;
    const int lane = tid & 63, wave = tid >> 6;
    const int nraw = ecnt[row];
    __shared__ float ws[4];

    if (nraw > ECAP) {
        const float4* rp = reinterpret_cast<const float4*>(adj + (size_t)row * NN);
        float sum = 0.f;
        for (int f = tid; f < NN / 4; f += 256) {
            float4 v = rp[f];
            sum += (v.x + v.y) + (v.z + v.w);
        }
#pragma unroll
        for (int off = 32; off > 0; off >>= 1) sum += __shfl_down(sum, off, 64);
        if (lane == 0) ws[wave] = sum;
        __syncthreads();
        if (tid == 0)
            sdeg[row] = 1.0f / (sqrtf(1.0f + ws[0] + ws[1] + ws[2] + ws[3]) + 1e-10f);
        return;
    }

    const int n = nraw;
    __shared__ int   lj[ECAP];
    __shared__ float lv[ECAP];
    __shared__ unsigned long long skey[ECAP];
    __shared__ int   oj[ECAP];
    __shared__ float ov[ECAP];
    if (tid < n) {
        int  jv = ej[(size_t)row * ECAP + tid];
        float vv = ev[(size_t)row * ECAP + tid];
        lj[tid] = jv; lv[tid] = vv;
        skey[tid] = ((unsigned long long)(unsigned)jv << 32) | (unsigned long long)ordkey(vv);
    }
    __syncthreads();
    if (tid < n) {
        unsigned long long mk = skey[tid];
        int rank = 0;
        for (int u = 0; u < n; ++u) {
            unsigned long long ku = skey[u];
            rank += (ku < mk || (ku == mk && u < tid)) ? 1 : 0;
        }
        oj[rank] = lj[tid];
        ov[rank] = lv[tid];
    }
    __syncthreads();
    if (tid < n) {
        ej[(size_t)row * ECAP + tid] = oj[tid];
        ev[(size_t)row * ECAP + tid] = ov[tid];
    }
    if (tid == 0) {
        float deg = 1.0f;
        for (int e = 0; e < n; ++e) deg += ov[e];
        sdeg[row] = 1.0f / (sqrtf(deg) + 1e-10f);
    }
}

// ---------------------------------------------------------------------------
// SpMM from sorted edge lists (deterministic); dense-scan fallback on ovf.
// ---------------------------------------------------------------------------
template<int COLS, bool DORELU>
__global__ __launch_bounds__(256)
void spmm_edges(const int* __restrict__ ej, const float* __restrict__ ev,
                const int* __restrict__ ecnt, const float* __restrict__ adj,
                const float* __restrict__ sdeg,
                const float* __restrict__ X, float* __restrict__ Y) {
    constexpr int CPT = COLS / 256;
    const int i = blockIdx.x;
    const int tid = threadIdx.x;
    const int lane = tid & 63, wave = tid >> 6;
    const float si = sdeg[i];
    const int nraw = ecnt[i];

    float acc[CPT];
#pragma unroll
    for (int c = 0; c < CPT; ++c) acc[c] = 0.f;

    if (nraw <= ECAP) {
        __shared__ int   s_j[ECAP];
        __shared__ float s_w[ECAP];
        if (tid < nraw) {
            int j = ej[(size_t)i * ECAP + tid];
            s_j[tid] = j;
            s_w[tid] = ev[(size_t)i * ECAP + tid] * sdeg[j];
        }
        __syncthreads();
#pragma unroll 4
        for (int e = 0; e < nraw; ++e) {
            int j = s_j[e];
            float we = s_w[e];
#pragma unroll
            for (int c = 0; c < CPT; ++c)
                acc[c] += we * X[(size_t)j * COLS + tid + c * 256];
        }
    } else {
        __shared__ int   s_j[256];
        __shared__ float s_w[256];
        __shared__ int   s_cnt[4];
        const float* rowp = adj + (size_t)i * NN;
        for (int j0 = 0; j0 < NN; j0 += 256) {
            float w = rowp[j0 + tid];
            bool nz = (w != 0.f);
            unsigned long long m = __ballot(nz);
            unsigned long long ltmask = (lane == 0) ? 0ull : (~0ull >> (64 - lane));
            int pre = __popcll(m & ltmask);
            if (lane == 0) s_cnt[wave] = __popcll(m);
            __syncthreads();
            int base = 0;
#pragma unroll
            for (int q = 0; q < 4; ++q)
                if (q < wave) base += s_cnt[q];
            int total = s_cnt[0] + s_cnt[1] + s_cnt[2] + s_cnt[3];
            if (nz) {
                int p = base + pre;
                s_j[p] = j0 + tid;
                s_w[p] = w * sdeg[j0 + tid];
            }
            __syncthreads();
            for (int e = 0; e < total; ++e) {
                int j = s_j[e];
                float we = s_w[e];
#pragma unroll
                for (int c = 0; c < CPT; ++c)
                    acc[c] += we * X[(size_t)j * COLS + tid + c * 256];
            }
            __syncthreads();
        }
    }

#pragma unroll
    for (int c = 0; c < CPT; ++c) {
        float val = si * (acc[c] + si * X[(size_t)i * COLS + tid + c * 256]);
        if (DORELU) val = fmaxf(val, 0.f);
        Y[(size_t)i * COLS + tid + c * 256] = val;
    }
}

// ---------------------------------------------------------------------------
extern "C" void kernel_launch(void* const* d_in, const int* in_sizes, int n_in,
                              void* d_out, int out_size, void* d_ws, size_t ws_size,
                              hipStream_t stream) {
    const float* features = (const float*)d_in[0];
    const float* masked   = (const float*)d_in[1];
    const float* W1  = (const float*)d_in[2];
    const float* b1  = (const float*)d_in[3];
    const float* W2  = (const float*)d_in[4];
    const float* b2  = (const float*)d_in[5];
    const float* Wg1 = (const float*)d_in[6];
    const float* bg1 = (const float*)d_in[7];
    const float* Wg2 = (const float*)d_in[8];
    const float* bg2 = (const float*)d_in[9];

    float* out_h3  = (float*)d_out;                      // [NN, DD]
    float* out_adj = (float*)d_out + (size_t)NN * DD;    // [NN, NN] (bf16 sim scratch too)
    unsigned short* simb = (unsigned short*)out_adj;     // bf16 sim view

    float* Areg = (float*)d_ws;
    float* Breg = Areg + (size_t)NN * DD;
    float* tail = Breg + (size_t)NN * DD;

    float* h    = Areg;
    unsigned short* ehi = (unsigned short*)Areg;          // NN*DD bf16
    unsigned short* mhi = (unsigned short*)Areg;          // NN*DD bf16
    unsigned short* mlo = mhi + (size_t)NN * DD;
    unsigned short* h1hi = (unsigned short*)Areg;         // NN*HH bf16
    unsigned short* h1lo = h1hi + (size_t)NN * HH;

    float* emb = Breg;
    float* x1  = Breg;                                    // [NN,HH] fp32
    float* h1  = Breg + (size_t)NN * HH;                  // [NN,HH] fp32
    float* x2  = Breg;                                    // [NN,DD] fp32

    float* tval = tail;                                   // NN*KTOP
    int*   tidx = (int*)(tval + (size_t)NN * KTOP);       // NN*KTOP
    float* sdeg = (float*)(tidx + (size_t)NN * KTOP);     // NN
    int*   ecnt = (int*)(sdeg + NN);                      // NN
    int*   elj  = ecnt + NN;                              // NN*ECAP
    float* elv  = (float*)(elj + (size_t)NN * ECAP);      // NN*ECAP
    unsigned short* wt1hi = (unsigned short*)(elv + (size_t)NN * ECAP); // HH*DD
    unsigned short* wt1lo = wt1hi + (size_t)HH * DD;
    unsigned short* wt2hi = wt1lo + (size_t)HH * DD;      // DD*HH
    unsigned short* wt2lo = wt2hi + (size_t)DD * HH;

    dim3 blk(256);

    // 1-2) MLP (fp32 — selection accuracy depends on emb)
    sgemm128<false, 1><<<dim3((NN / 128) * (DD / 128)), blk, 0, stream>>>(
        features, W1, b1, h, NN, DD, DD);
    sgemm128<false, 0><<<dim3((NN / 128) * (DD / 128)), blk, 0, stream>>>(
        h, W2, b2, emb, NN, DD, DD);
    // 3) normalize + emit bf16 (h dead -> ehi overlays it)
    rownorm_emit_kernel<<<dim3(NN), blk, 0, stream>>>(emb, ehi);
    // 4) approx sim (bf16 in/out) -> out_adj scratch
    simgemm_bf16<<<dim3(4096), blk, 0, stream>>>(ehi, simb);
    // 5) clear edge counters, then fused candidate-select + refine + edge push
    hipMemsetAsync(ecnt, 0, (size_t)NN * sizeof(int), stream);
    topk_refine_kernel<<<dim3(NN), blk, 0, stream>>>(
        simb, emb, tidx, tval, ecnt, elj, elv);
    // 6) zero adjacency (grid-stride, high-BW; after sim is consumed)
    zero_kernel<<<dim3(2048), blk, 0, stream>>>((float4*)out_adj);
    // 7) dense scatter of topk edges (deterministic atomics)
    scatter_dense<<<dim3((NN * KTOP + 255) / 256), blk, 0, stream>>>(
        tidx, tval, out_adj);
    // 8) sort edge lists + degrees (dense fallback reads final adj)
    sortdeg_kernel<<<dim3(NN), blk, 0, stream>>>(elj, elv, ecnt, out_adj, sdeg);
    // 9-11) x1 = masked @ Wg1 + bg1 via bf16x3 MFMA
    split_kernel<<<dim3(NN * DD / 1024), blk, 0, stream>>>(masked, mhi, mlo);
    wtrans_kernel<<<dim3(DD * HH / 256), blk, 0, stream>>>(Wg1, wt1hi, wt1lo, DD, HH);
    mfma_nt_bias<DD><<<dim3((NN / 128) * (HH / 128)), blk, 0, stream>>>(
        mhi, mlo, wt1hi, wt1lo, bg1, x1, HH);
    // 12) h1 = relu(Ahat @ x1)
    spmm_edges<HH, true><<<dim3(NN), blk, 0, stream>>>(
        elj, elv, ecnt, out_adj, sdeg, x1, h1);
    // 13-15) x2 = h1 @ Wg2 + bg2 via bf16x3 MFMA
    split_kernel<<<dim3(NN * HH / 1024), blk, 0, stream>>>(h1, h1hi, h1lo);
    wtrans_kernel<<<dim3(HH * DD / 256), blk, 0, stream>>>(Wg2, wt2hi, wt2lo, HH, DD);
    mfma_nt_bias<HH><<<dim3((NN / 128) * (DD / 128)), blk, 0, stream>>>(
        h1hi, h1lo, wt2hi, wt2lo, bg2, x2, DD);
    // 16) h3 = Ahat @ x2 -> d_out
    spmm_edges<DD, false><<<dim3(NN), blk, 0, stream>>>(
        elj, elv, ecnt, out_adj, sdeg, x2, out_h3);
}

// Round 8
// 734.666 us; speedup vs baseline: 1.4462x; 1.0143x over previous
//
#include <hip/hip_runtime.h>
#include <cstdint>
#include <cstddef>

#define NN 8192
#define DD 512
#define HH 256
#define KTOP 21
#define CCAP 192   // candidate collection capacity
#define CMIN 48    // minimum candidates (superset of top-21 w/ bf16 margin)
#define ECAP 224   // per-row edge-list capacity
#define NBIN 1024
#define BFLOOR 1   // don't histogram bin 0 (55% of mass -> LDS atomic serialization)

typedef __attribute__((ext_vector_type(8))) __bf16 bf16x8;
typedef __attribute__((ext_vector_type(4))) float f32x4;

__device__ __forceinline__ unsigned short f2bf(float x) {
    unsigned u = __float_as_uint(x);
    u += 0x7fffu + ((u >> 16) & 1u);
    return (unsigned short)(u >> 16);
}
__device__ __forceinline__ float bf2f(unsigned short h) {
    return __uint_as_float(((unsigned)h) << 16);
}
// order-preserving key: monotone map float -> uint (used by sort_write)
__device__ __forceinline__ unsigned ordkey(float x) {
    unsigned b = __float_as_uint(x);
    return b ^ (((int)b >> 31) | 0x80000000u);
}

#define GLD16(gp, lp) __builtin_amdgcn_global_load_lds( \
    (const __attribute__((address_space(1))) unsigned int*)(gp), \
    (__attribute__((address_space(3))) unsigned int*)(lp), 16, 0, 0)

// ---------------------------------------------------------------------------
// fp32 SGEMM: GEMM1/2 (emb path must stay fp32-exact for selection)
// ---------------------------------------------------------------------------
template<bool TRANSB, int ACT>
__global__ __launch_bounds__(256)
void sgemm128(const float* __restrict__ A, const float* __restrict__ B,
              const float* __restrict__ bias, float* __restrict__ C,
              int M, int N, int K) {
    constexpr int BM = 128, BN = 128, BK = 16;
    __shared__ float As[BK][BM + 4];
    __shared__ float Bs[BK][BN + 4];

    const int tiles_n = N / BN;
    const int by = blockIdx.x / tiles_n;
    const int bx = blockIdx.x % tiles_n;
    const int row0 = by * BM, col0 = bx * BN;
    const int tid = threadIdx.x;
    const int tx = tid & 15, ty = tid >> 4;

    float acc[8][8];
#pragma unroll
    for (int m = 0; m < 8; ++m)
#pragma unroll
        for (int n = 0; n < 8; ++n) acc[m][n] = 0.f;

    for (int k0 = 0; k0 < K; k0 += BK) {
#pragma unroll
        for (int l = 0; l < 2; ++l) {
            int f = tid + l * 256;
            int r = f >> 2, c4 = f & 3;
            float4 v = *reinterpret_cast<const float4*>(
                A + (size_t)(row0 + r) * K + k0 + c4 * 4);
            As[c4 * 4 + 0][r] = v.x;
            As[c4 * 4 + 1][r] = v.y;
            As[c4 * 4 + 2][r] = v.z;
            As[c4 * 4 + 3][r] = v.w;
        }
        if (TRANSB) {
#pragma unroll
            for (int l = 0; l < 2; ++l) {
                int f = tid + l * 256;
                int r = f >> 2, c4 = f & 3;
                float4 v = *reinterpret_cast<const float4*>(
                    B + (size_t)(col0 + r) * K + k0 + c4 * 4);
                Bs[c4 * 4 + 0][r] = v.x;
                Bs[c4 * 4 + 1][r] = v.y;
                Bs[c4 * 4 + 2][r] = v.z;
                Bs[c4 * 4 + 3][r] = v.w;
            }
        } else {
#pragma unroll
            for (int l = 0; l < 2; ++l) {
                int f = tid + l * 256;
                int kr = f >> 5, n4 = f & 31;
                *reinterpret_cast<float4*>(&Bs[kr][n4 * 4]) =
                    *reinterpret_cast<const float4*>(
                        B + (size_t)(k0 + kr) * N + col0 + n4 * 4);
            }
        }
        __syncthreads();

#pragma unroll
        for (int kk = 0; kk < BK; ++kk) {
            float a[8], b[8];
            *(float4*)&a[0] = *(const float4*)&As[kk][ty * 8];
            *(float4*)&a[4] = *(const float4*)&As[kk][ty * 8 + 4];
            *(float4*)&b[0] = *(const float4*)&Bs[kk][tx * 8];
            *(float4*)&b[4] = *(const float4*)&Bs[kk][tx * 8 + 4];
#pragma unroll
            for (int m = 0; m < 8; ++m)
#pragma unroll
                for (int n = 0; n < 8; ++n)
                    acc[m][n] = fmaf(a[m], b[n], acc[m][n]);
        }
        __syncthreads();
    }

    const int crow = row0 + ty * 8;
    const int ccol = col0 + tx * 8;
    float bv[8];
#pragma unroll
    for (int n = 0; n < 8; ++n) bv[n] = bias ? bias[ccol + n] : 0.f;
#pragma unroll
    for (int m = 0; m < 8; ++m) {
        float o[8];
#pragma unroll
        for (int n = 0; n < 8; ++n) {
            float t = acc[m][n] + bv[n];
            if (ACT == 1) t = fmaxf(t, 0.f);
            o[n] = t;
        }
        *reinterpret_cast<float4*>(C + (size_t)(crow + m) * N + ccol)     = *(float4*)&o[0];
        *reinterpret_cast<float4*>(C + (size_t)(crow + m) * N + ccol + 4) = *(float4*)&o[4];
    }
}

// ---------------------------------------------------------------------------
// Row L2-normalize + emit bf16 copy
// ---------------------------------------------------------------------------
__global__ __launch_bounds__(256)
void rownorm_emit_kernel(float* __restrict__ emb, unsigned short* __restrict__ ehi) {
    const int row = blockIdx.x, tid = threadIdx.x;
    float* rp = emb + (size_t)row * DD;
    float v0 = rp[tid], v1 = rp[tid + 256];
    float sum = v0 * v0 + v1 * v1;
#pragma unroll
    for (int off = 32; off > 0; off >>= 1) sum += __shfl_down(sum, off, 64);
    __shared__ float ws[4];
    __shared__ float sc_sh;
    if ((tid & 63) == 0) ws[tid >> 6] = sum;
    __syncthreads();
    if (tid == 0) {
        float n = sqrtf(ws[0] + ws[1] + ws[2] + ws[3]);
        sc_sh = 1.0f / fmaxf(n, 1e-12f);
    }
    __syncthreads();
    float sc = sc_sh;
    v0 *= sc; v1 *= sc;
    rp[tid] = v0;
    rp[tid + 256] = v1;
    ehi[(size_t)row * DD + tid]       = f2bf(v0);
    ehi[(size_t)row * DD + tid + 256] = f2bf(v1);
}

// ---------------------------------------------------------------------------
// Split fp32 -> (hi, lo) bf16 pair
// ---------------------------------------------------------------------------
__global__ __launch_bounds__(256)
void split_kernel(const float* __restrict__ e, unsigned short* __restrict__ hi,
                  unsigned short* __restrict__ lo) {
    const int i = (blockIdx.x * 256 + threadIdx.x) * 4;
    float4 v = *reinterpret_cast<const float4*>(e + i);
    ushort4 h, l;
    h.x = f2bf(v.x); l.x = f2bf(v.x - bf2f(h.x));
    h.y = f2bf(v.y); l.y = f2bf(v.y - bf2f(h.y));
    h.z = f2bf(v.z); l.z = f2bf(v.z - bf2f(h.z));
    h.w = f2bf(v.w); l.w = f2bf(v.w - bf2f(h.w));
    *reinterpret_cast<ushort4*>(hi + i) = h;
    *reinterpret_cast<ushort4*>(lo + i) = l;
}

// ---------------------------------------------------------------------------
// Transpose + split weights: W [K,N] fp32 -> Thi/Tlo [N,K] bf16
// ---------------------------------------------------------------------------
__global__ __launch_bounds__(256)
void wtrans_kernel(const float* __restrict__ W, unsigned short* __restrict__ Thi,
                   unsigned short* __restrict__ Tlo, int K, int N) {
    int t = blockIdx.x * 256 + threadIdx.x;
    if (t >= K * N) return;
    int k = t / N, n = t - k * N;
    float x = W[t];
    unsigned short h = f2bf(x);
    Thi[(size_t)n * K + k] = h;
    Tlo[(size_t)n * K + k] = f2bf(x - bf2f(h));
}

// ---------------------------------------------------------------------------
// approx sim = Ehi * Ehi^T (single bf16 MFMA product), bf16 output,
// LDS-staged coalesced epilogue (two 64-row phases reuse the A/B LDS).
// ---------------------------------------------------------------------------
__global__ __launch_bounds__(256)
void simgemm_bf16(const unsigned short* __restrict__ Ehi,
                  unsigned short* __restrict__ Cb) {
    const int bid = blockIdx.x;
    const int swz = (bid & 7) * 512 + (bid >> 3);
    const int by = swz >> 6, bx = swz & 63;

    __shared__ unsigned short SB[8192];   // 16 KB: A/B staging, then epilogue
    unsigned short* Ah = SB;              // 128*32
    unsigned short* Bh = SB + 4096;       // 128*32

    const int tid = threadIdx.x, lane = tid & 63, wid = tid >> 6;
    const int wm = wid >> 1, wn = wid & 1;
    const int fr = lane & 15, fq = lane >> 4;
    const int lrow = lane >> 2;
    const int lcol8 = (lane & 3) * 8;

    const size_t arow0 = (size_t)by * 128;
    const size_t brow0 = (size_t)bx * 128;

    f32x4 acc[4][4];
#pragma unroll
    for (int m = 0; m < 4; ++m)
#pragma unroll
        for (int n = 0; n < 4; ++n) acc[m][n] = (f32x4){0.f, 0.f, 0.f, 0.f};

    for (int k0 = 0; k0 < DD; k0 += 32) {
#pragma unroll
        for (int i = 0; i < 2; ++i) {
            const int chunk = wid + i * 4;
            const int grow = chunk * 16 + lrow;
            GLD16(Ehi + (arow0 + grow) * DD + (k0 + lcol8), Ah + chunk * 512);
            GLD16(Ehi + (brow0 + grow) * DD + (k0 + lcol8), Bh + chunk * 512);
        }
        __syncthreads();

        bf16x8 ah[4], bh[4];
#pragma unroll
        for (int mf = 0; mf < 4; ++mf)
            ah[mf] = *(const bf16x8*)&Ah[(wm * 64 + mf * 16 + fr) * 32 + fq * 8];
#pragma unroll
        for (int nf = 0; nf < 4; ++nf)
            bh[nf] = *(const bf16x8*)&Bh[(wn * 64 + nf * 16 + fr) * 32 + fq * 8];
#pragma unroll
        for (int mf = 0; mf < 4; ++mf)
#pragma unroll
            for (int nf = 0; nf < 4; ++nf)
                acc[mf][nf] = __builtin_amdgcn_mfma_f32_16x16x32_bf16(ah[mf], bh[nf], acc[mf][nf], 0, 0, 0);
        __syncthreads();
    }

    // epilogue: two phases of 64 rows; stage bf16 tile in LDS, stream out 16B/lane
#pragma unroll
    for (int ph = 0; ph < 2; ++ph) {
        if (wm == ph) {
#pragma unroll
            for (int mf = 0; mf < 4; ++mf)
#pragma unroll
                for (int nf = 0; nf < 4; ++nf)
#pragma unroll
                    for (int r2 = 0; r2 < 4; ++r2)
                        SB[(mf * 16 + fq * 4 + r2) * 128 + wn * 64 + nf * 16 + fr] =
                            f2bf(acc[mf][nf][r2]);
        }
        __syncthreads();
#pragma unroll
        for (int it = 0; it < 4; ++it) {
            int flat = it * 256 + tid;
            int rowL = flat >> 4, cc = flat & 15;
            *reinterpret_cast<uint4*>(
                &Cb[(arow0 + ph * 64 + rowL) * NN + (size_t)bx * 128 + cc * 8]) =
                *reinterpret_cast<const uint4*>(&SB[rowL * 128 + cc * 8]);
        }
        __syncthreads();
    }
}

// ---------------------------------------------------------------------------
// bf16x3 MFMA GEMM (NT) with bias: x1/x2 path
// ---------------------------------------------------------------------------
template<int KDIM>
__global__ __launch_bounds__(256)
void mfma_nt_bias(const unsigned short* __restrict__ Ahi,
                  const unsigned short* __restrict__ Alo,
                  const unsigned short* __restrict__ Bhi,
                  const unsigned short* __restrict__ Blo,
                  const float* __restrict__ bias, float* __restrict__ C, int N) {
    const int tiles_n = N / 128;
    const int by = blockIdx.x / tiles_n, bx = blockIdx.x % tiles_n;

    __shared__ unsigned short Ah[128 * 32];
    __shared__ unsigned short Al[128 * 32];
    __shared__ unsigned short Bh[128 * 32];
    __shared__ unsigned short Bl[128 * 32];

    const int tid = threadIdx.x, lane = tid & 63, wid = tid >> 6;
    const int wm = wid >> 1, wn = wid & 1;
    const int fr = lane & 15, fq = lane >> 4;
    const int lrow = lane >> 2;
    const int lcol8 = (lane & 3) * 8;

    const size_t arow0 = (size_t)by * 128;
    const size_t brow0 = (size_t)bx * 128;

    f32x4 acc[4][4];
#pragma unroll
    for (int m = 0; m < 4; ++m)
#pragma unroll
        for (int n = 0; n < 4; ++n) acc[m][n] = (f32x4){0.f, 0.f, 0.f, 0.f};

    for (int k0 = 0; k0 < KDIM; k0 += 32) {
#pragma unroll
        for (int i = 0; i < 2; ++i) {
            const int chunk = wid + i * 4;
            const int grow = chunk * 16 + lrow;
            GLD16(Ahi + (arow0 + grow) * KDIM + (k0 + lcol8), Ah + chunk * 512);
            GLD16(Alo + (arow0 + grow) * KDIM + (k0 + lcol8), Al + chunk * 512);
            GLD16(Bhi + (brow0 + grow) * KDIM + (k0 + lcol8), Bh + chunk * 512);
            GLD16(Blo + (brow0 + grow) * KDIM + (k0 + lcol8), Bl + chunk * 512);
        }
        __syncthreads();

        bf16x8 ah[4], al[4], bh[4], bl[4];
#pragma unroll
        for (int mf = 0; mf < 4; ++mf) {
            const int r = wm * 64 + mf * 16 + fr;
            ah[mf] = *(const bf16x8*)&Ah[r * 32 + fq * 8];
            al[mf] = *(const bf16x8*)&Al[r * 32 + fq * 8];
        }
#pragma unroll
        for (int nf = 0; nf < 4; ++nf) {
            const int r = wn * 64 + nf * 16 + fr;
            bh[nf] = *(const bf16x8*)&Bh[r * 32 + fq * 8];
            bl[nf] = *(const bf16x8*)&Bl[r * 32 + fq * 8];
        }
#pragma unroll
        for (int mf = 0; mf < 4; ++mf)
#pragma unroll
            for (int nf = 0; nf < 4; ++nf) {
                acc[mf][nf] = __builtin_amdgcn_mfma_f32_16x16x32_bf16(ah[mf], bh[nf], acc[mf][nf], 0, 0, 0);
                acc[mf][nf] = __builtin_amdgcn_mfma_f32_16x16x32_bf16(ah[mf], bl[nf], acc[mf][nf], 0, 0, 0);
                acc[mf][nf] = __builtin_amdgcn_mfma_f32_16x16x32_bf16(al[mf], bh[nf], acc[mf][nf], 0, 0, 0);
            }
        __syncthreads();
    }

#pragma unroll
    for (int mf = 0; mf < 4; ++mf) {
#pragma unroll
        for (int nf = 0; nf < 4; ++nf) {
            const size_t row = arow0 + wm * 64 + mf * 16 + fq * 4;
            const int col = bx * 128 + wn * 64 + nf * 16 + fr;
            const float bv = bias[col];
#pragma unroll
            for (int r2 = 0; r2 < 4; ++r2)
                C[(row + r2) * N + col] = acc[mf][nf][r2] + bv;
        }
    }
}

// ---------------------------------------------------------------------------
// FUSED: histogram candidate selection + exact fp32 refine + top-21 + edge push
// Bin 0 (55% of the mass: negatives + tiny positives) is NOT histogrammed —
// it caused ~4500 serialized same-address LDS atomics per block. Counts for
// bins >= BFLOOR are exact, so b* >= BFLOOR selection is bit-identical.
// ---------------------------------------------------------------------------
__global__ __launch_bounds__(256)
void topk_refine_kernel(const unsigned short* __restrict__ simb,
                        const float* __restrict__ emb,
                        int* __restrict__ tidx, float* __restrict__ tval,
                        int* __restrict__ ecnt, int* __restrict__ elj,
                        float* __restrict__ elv) {
    const int row = blockIdx.x;
    const int tid = threadIdx.x;
    const int lane = tid & 63, wave = tid >> 6;

    // ---- phase 1: load row, histogram, threshold ----
    const uint4* rp = reinterpret_cast<const uint4*>(simb + (size_t)row * NN);
    uint4 q[4];
#pragma unroll
    for (int t = 0; t < 4; ++t) q[t] = rp[t * 256 + tid];
    unsigned pk[16];
#pragma unroll
    for (int t = 0; t < 4; ++t) {
        pk[t * 4 + 0] = q[t].x; pk[t * 4 + 1] = q[t].y;
        pk[t * 4 + 2] = q[t].z; pk[t * 4 + 3] = q[t].w;
    }

    __shared__ int hist[NBIN];
    for (int b = tid; b < NBIN; b += 256) hist[b] = 0;
    __syncthreads();

    short bins[32];
#pragma unroll
    for (int u = 0; u < 16; ++u) {
        float flo = __uint_as_float(pk[u] << 16);
        float fhi = __uint_as_float(pk[u] & 0xFFFF0000u);
        int blo = (int)(flo * (float)NBIN); blo = max(0, min(NBIN - 1, blo));
        int bhi = (int)(fhi * (float)NBIN); bhi = max(0, min(NBIN - 1, bhi));
        bins[u * 2]     = (short)blo;
        bins[u * 2 + 1] = (short)bhi;
        if (blo >= BFLOOR) atomicAdd(&hist[blo], 1);
        if (bhi >= BFLOOR) atomicAdd(&hist[bhi], 1);
    }
    __syncthreads();

    __shared__ int s_bstar;
    if (wave == 0) {
        int cum = 0, found = -1;
        for (int c0 = NBIN - 1; c0 >= 0 && found < 0; c0 -= 64) {
            int b = c0 - lane;
            int cnt = (b >= 0) ? hist[b] : 0;
            int sc = cnt;
#pragma unroll
            for (int off = 1; off < 64; off <<= 1) {
                int o = __shfl_up(sc, off, 64);
                if (lane >= off) sc += o;
            }
            int chunk_total = __shfl(sc, 63, 64);
            bool hit = (cum + sc >= CMIN);
            unsigned long long mh = __ballot(hit);
            if (mh) found = c0 - (__ffsll((long long)mh) - 1);
            else cum += chunk_total;
        }
        if (found < 0) found = 0;
        if (lane == 0) s_bstar = found;
    }
    __syncthreads();
    const int bstar = s_bstar;

    // ---- phase 2: deterministic compaction of candidates into LDS ----
    __shared__ int s_cand[CCAP];
    int cnt = 0;
#pragma unroll
    for (int i = 0; i < 32; ++i) cnt += (bins[i] >= bstar) ? 1 : 0;
    int sc = cnt;
#pragma unroll
    for (int off = 1; off < 64; off <<= 1) {
        int o = __shfl_up(sc, off, 64);
        if (lane >= off) sc += o;
    }
    __shared__ int wtot[4];
    if (lane == 63) wtot[wave] = sc;
    __syncthreads();
    int base = sc - cnt;
#pragma unroll
    for (int w = 0; w < 4; ++w)
        if (w < wave) base += wtot[w];
    int total = wtot[0] + wtot[1] + wtot[2] + wtot[3];

    int pos = base;
#pragma unroll
    for (int u = 0; u < 16; ++u) {
#pragma unroll
        for (int h = 0; h < 2; ++h) {
            if (bins[u * 2 + h] >= bstar) {
                if (pos < CCAP)
                    s_cand[pos] = ((u >> 2) * 256 + tid) * 8 + (u & 3) * 2 + h;
                pos++;
            }
        }
    }
    __syncthreads();
    const int ncand = min(total, CCAP);

    // ---- phase 3: exact fp32 dots for candidates ----
    __shared__ float sval[CCAP];
    __shared__ int   sidx[CCAP];
    const float* ei = emb + (size_t)row * DD;
    float4 a0 = reinterpret_cast<const float4*>(ei)[lane * 2];
    float4 a1 = reinterpret_cast<const float4*>(ei)[lane * 2 + 1];

    for (int base2 = wave * 2; base2 < ncand; base2 += 8) {
#pragma unroll
        for (int qq = 0; qq < 2; ++qq) {
            int c = base2 + qq;
            if (c >= ncand) break;
            const int j = s_cand[c];
            const float* ej = emb + (size_t)j * DD;
            float4 b0 = reinterpret_cast<const float4*>(ej)[lane * 2];
            float4 b1 = reinterpret_cast<const float4*>(ej)[lane * 2 + 1];
            float s = 0.f;
            s = fmaf(a0.x, b0.x, s); s = fmaf(a0.y, b0.y, s);
            s = fmaf(a0.z, b0.z, s); s = fmaf(a0.w, b0.w, s);
            s = fmaf(a1.x, b1.x, s); s = fmaf(a1.y, b1.y, s);
            s = fmaf(a1.z, b1.z, s); s = fmaf(a1.w, b1.w, s);
#pragma unroll
            for (int off = 32; off > 0; off >>= 1) s += __shfl_xor(s, off, 64);
            if (lane == 0) { sval[c] = s; sidx[c] = j; }
        }
    }
    __syncthreads();

    // ---- phase 4: wave0 selects top-21 (value desc, idx asc) ----
    __shared__ float selv[KTOP];
    __shared__ int   seli[KTOP];
    if (wave == 0) {
        float v[3]; int id[3];
#pragma unroll
        for (int k = 0; k < 3; ++k) {
            int s = lane + 64 * k;
            if (s < ncand) { v[k] = sval[s]; id[k] = sidx[s]; }
            else           { v[k] = -INFINITY; id[k] = 0x7fffffff; }
        }
#pragma unroll 1
        for (int sel = 0; sel < KTOP; ++sel) {
            float bv = v[0]; int bi = id[0];
#pragma unroll
            for (int k = 1; k < 3; ++k)
                if (v[k] > bv || (v[k] == bv && id[k] < bi)) { bv = v[k]; bi = id[k]; }
#pragma unroll
            for (int off = 1; off < 64; off <<= 1) {
                float ov = __shfl_xor(bv, off, 64);
                int   oi = __shfl_xor(bi, off, 64);
                if (ov > bv || (ov == bv && oi < bi)) { bv = ov; bi = oi; }
            }
            if (lane == 0) { selv[sel] = bv; seli[sel] = bi; }
#pragma unroll
            for (int k = 0; k < 3; ++k)
                if (id[k] == bi) { v[k] = -INFINITY; id[k] = 0x7fffffff; }
        }
    }
    __syncthreads();

    // ---- phase 5: write topk + push edges into lists ----
    if (tid < KTOP) {
        float bv = selv[tid];
        int   bi = seli[tid];
        tval[(size_t)row * KTOP + tid] = bv;
        tidx[(size_t)row * KTOP + tid] = bi;
        if (bi != row && bi >= 0 && bi < NN && bv > 0.f) {
            float v = bv * 0.5f;
            int pi = atomicAdd(ecnt + row, 1);
            if (pi < ECAP) { elj[(size_t)row * ECAP + pi] = bi; elv[(size_t)row * ECAP + pi] = v; }
            int pj = atomicAdd(ecnt + bi, 1);
            if (pj < ECAP) { elj[(size_t)bi * ECAP + pj] = row; elv[(size_t)bi * ECAP + pj] = v; }
        }
    }
}

// ---------------------------------------------------------------------------
// FUSED adjacency materialization: per row — zero the 32 KB row (coalesced,
// no LDS row buffer), sort the edge list by (j, valbits), compute sdeg, and
// write deduped edge values (runs of equal j are bitwise-equal pairs =>
// deterministic sum). Overflow rows are only zeroed; ovf_fix/ovf_deg finish.
// ---------------------------------------------------------------------------
__global__ __launch_bounds__(256)
void sort_write_kernel(int* __restrict__ ej, float* __restrict__ ev,
                       const int* __restrict__ ecnt,
                       float* __restrict__ adj, float* __restrict__ sdeg) {
    const int row = blockIdx.x, tid = threadIdx.x;
    const int nraw = ecnt[row];

    float4* out4 = reinterpret_cast<float4*>(adj + (size_t)row * NN);
    const float4 z = {0.f, 0.f, 0.f, 0.f};
#pragma unroll
    for (int f = tid; f < NN / 4; f += 256) out4[f] = z;

    if (nraw > ECAP) return;   // overflow: fixup kernels handle fill + degree

    const int n = nraw;
    __shared__ int   lj[ECAP];
    __shared__ float lv[ECAP];
    __shared__ unsigned long long skey[ECAP];
    __shared__ int   oj[ECAP];
    __shared__ float ov[ECAP];
    if (tid < n) {
        int  jv = ej[(size_t)row * ECAP + tid];
        float vv = ev[(size_t)row * ECAP + tid];
        lj[tid] = jv; lv[tid] = vv;
        skey[tid] = ((unsigned long long)(unsigned)jv << 32) | (unsigned long long)ordkey(vv);
    }
    __syncthreads();
    if (tid < n) {
        unsigned long long mk = skey[tid];
        int rank = 0;
        for (int u = 0; u < n; ++u) {
            unsigned long long ku = skey[u];
            rank += (ku < mk || (ku == mk && u < tid)) ? 1 : 0;
        }
        oj[rank] = lj[tid];
        ov[rank] = lv[tid];
    }
    __syncthreads();
    if (tid < n) {
        ej[(size_t)row * ECAP + tid] = oj[tid];
        ev[(size_t)row * ECAP + tid] = ov[tid];
    }
    if (tid == 0) {
        float deg = 1.0f;
        for (int e = 0; e < n; ++e) deg += ov[e];
        sdeg[row] = 1.0f / (sqrtf(deg) + 1e-10f);
    }
    __syncthreads();   // row zeros + sorted arrays visible block-wide
    if (tid < n) {
        int j = oj[tid];
        if (tid == 0 || oj[tid - 1] != j) {       // first of run writes run-sum
            float s = ov[tid];
            if (tid + 1 < n && oj[tid + 1] == j) s += ov[tid + 1];
            adj[(size_t)row * NN + j] = s;
        }
    }
}

// ---------------------------------------------------------------------------
// Overflow fixups: fill overflow rows from the full topk tables (<=2
// bitwise-equal addends per cell => deterministic), then their degrees.
// ---------------------------------------------------------------------------
__global__ __launch_bounds__(256)
void ovf_fix_kernel(const int* __restrict__ tidx, const float* __restrict__ tval,
                    const int* __restrict__ ecnt, float* __restrict__ adj) {
    int t = blockIdx.x * 256 + threadIdx.x;
    if (t >= NN * KTOP) return;
    int i = t / KTOP;
    int j = tidx[t];
    if (j == i || j < 0) return;
    float v = tval[t];
    if (v <= 0.f) return;
    v *= 0.5f;
    if (ecnt[i] > ECAP) atomicAdd(adj + (size_t)i * NN + j, v);
    if (ecnt[j] > ECAP) atomicAdd(adj + (size_t)j * NN + i, v);
}

__global__ __launch_bounds__(256)
void ovf_deg_kernel(const int* __restrict__ ecnt, const float* __restrict__ adj,
                    float* __restrict__ sdeg) {
    const int row = blockIdx.x, tid = threadIdx.x;
    if (ecnt[row] <= ECAP) return;
    const int lane = tid & 63, wave = tid >> 6;
    const float4* rp = reinterpret_cast<const float4*>(adj + (size_t)row * NN);
    float sum = 0.f;
    for (int f = tid; f < NN / 4; f += 256) {
        float4 v = rp[f];
        sum += (v.x + v.y) + (v.z + v.w);
    }
#pragma unroll
    for (int off = 32; off > 0; off >>= 1) sum += __shfl_down(sum, off, 64);
    __shared__ float ws[4];
    if (lane == 0) ws[wave] = sum;
    __syncthreads();
    if (tid == 0)
        sdeg[row] = 1.0f / (sqrtf(1.0f + ws[0] + ws[1] + ws[2] + ws[3]) + 1e-10f);
}

// ---------------------------------------------------------------------------
// SpMM from sorted edge lists (deterministic); dense-scan fallback on ovf.
// ---------------------------------------------------------------------------
template<int COLS, bool DORELU>
__global__ __launch_bounds__(256)
void spmm_edges(const int* __restrict__ ej, const float* __restrict__ ev,
                const int* __restrict__ ecnt, const float* __restrict__ adj,
                const float* __restrict__ sdeg,
                const float* __restrict__ X, float* __restrict__ Y) {
    constexpr int CPT = COLS / 256;
    const int i = blockIdx.x;
    const int tid = threadIdx.x;
    const int lane = tid & 63, wave = tid >> 6;
    const float si = sdeg[i];
    const int nraw = ecnt[i];

    float acc[CPT];
#pragma unroll
    for (int c = 0; c < CPT; ++c) acc[c] = 0.f;

    if (nraw <= ECAP) {
        __shared__ int   s_j[ECAP];
        __shared__ float s_w[ECAP];
        if (tid < nraw) {
            int j = ej[(size_t)i * ECAP + tid];
            s_j[tid] = j;
            s_w[tid] = ev[(size_t)i * ECAP + tid] * sdeg[j];
        }
        __syncthreads();
#pragma unroll 4
        for (int e = 0; e < nraw; ++e) {
            int j = s_j[e];
            float we = s_w[e];
#pragma unroll
            for (int c = 0; c < CPT; ++c)
                acc[c] += we * X[(size_t)j * COLS + tid + c * 256];
        }
    } else {
        __shared__ int   s_j[256];
        __shared__ float s_w[256];
        __shared__ int   s_cnt[4];
        const float* rowp = adj + (size_t)i * NN;
        for (int j0 = 0; j0 < NN; j0 += 256) {
            float w = rowp[j0 + tid];
            bool nz = (w != 0.f);
            unsigned long long m = __ballot(nz);
            unsigned long long ltmask = (lane == 0) ? 0ull : (~0ull >> (64 - lane));
            int pre = __popcll(m & ltmask);
            if (lane == 0) s_cnt[wave] = __popcll(m);
            __syncthreads();
            int base = 0;
#pragma unroll
            for (int q = 0; q < 4; ++q)
                if (q < wave) base += s_cnt[q];
            int total = s_cnt[0] + s_cnt[1] + s_cnt[2] + s_cnt[3];
            if (nz) {
                int p = base + pre;
                s_j[p] = j0 + tid;
                s_w[p] = w * sdeg[j0 + tid];
            }
            __syncthreads();
            for (int e = 0; e < total; ++e) {
                int j = s_j[e];
                float we = s_w[e];
#pragma unroll
                for (int c = 0; c < CPT; ++c)
                    acc[c] += we * X[(size_t)j * COLS + tid + c * 256];
            }
            __syncthreads();
        }
    }

#pragma unroll
    for (int c = 0; c < CPT; ++c) {
        float val = si * (acc[c] + si * X[(size_t)i * COLS + tid + c * 256]);
        if (DORELU) val = fmaxf(val, 0.f);
        Y[(size_t)i * COLS + tid + c * 256] = val;
    }
}

// ---------------------------------------------------------------------------
extern "C" void kernel_launch(void* const* d_in, const int* in_sizes, int n_in,
                              void* d_out, int out_size, void* d_ws, size_t ws_size,
                              hipStream_t stream) {
    const float* features = (const float*)d_in[0];
    const float* masked   = (const float*)d_in[1];
    const float* W1  = (const float*)d_in[2];
    const float* b1  = (const float*)d_in[3];
    const float* W2  = (const float*)d_in[4];
    const float* b2  = (const float*)d_in[5];
    const float* Wg1 = (const float*)d_in[6];
    const float* bg1 = (const float*)d_in[7];
    const float* Wg2 = (const float*)d_in[8];
    const float* bg2 = (const float*)d_in[9];

    float* out_h3  = (float*)d_out;                      // [NN, DD]
    float* out_adj = (float*)d_out + (size_t)NN * DD;    // [NN, NN] (bf16 sim scratch too)
    unsigned short* simb = (unsigned short*)out_adj;     // bf16 sim view

    float* Areg = (float*)d_ws;
    float* Breg = Areg + (size_t)NN * DD;
    float* tail = Breg + (size_t)NN * DD;

    float* h    = Areg;
    unsigned short* ehi = (unsigned short*)Areg;          // NN*DD bf16
    unsigned short* mhi = (unsigned short*)Areg;          // NN*DD bf16
    unsigned short* mlo = mhi + (size_t)NN * DD;
    unsigned short* h1hi = (unsigned short*)Areg;         // NN*HH bf16
    unsigned short* h1lo = h1hi + (size_t)NN * HH;

    float* emb = Breg;
    float* x1  = Breg;                                    // [NN,HH] fp32
    float* h1  = Breg + (size_t)NN * HH;                  // [NN,HH] fp32
    float* x2  = Breg;                                    // [NN,DD] fp32

    float* tval = tail;                                   // NN*KTOP
    int*   tidx = (int*)(tval + (size_t)NN * KTOP);       // NN*KTOP
    float* sdeg = (float*)(tidx + (size_t)NN * KTOP);     // NN
    int*   ecnt = (int*)(sdeg + NN);                      // NN
    int*   elj  = ecnt + NN;                              // NN*ECAP
    float* elv  = (float*)(elj + (size_t)NN * ECAP);      // NN*ECAP
    unsigned short* wt1hi = (unsigned short*)(elv + (size_t)NN * ECAP); // HH*DD
    unsigned short* wt1lo = wt1hi + (size_t)HH * DD;
    unsigned short* wt2hi = wt1lo + (size_t)HH * DD;      // DD*HH
    unsigned short* wt2lo = wt2hi + (size_t)DD * HH;

    dim3 blk(256);

    // 1-2) MLP (fp32 — selection accuracy depends on emb)
    sgemm128<false, 1><<<dim3((NN / 128) * (DD / 128)), blk, 0, stream>>>(
        features, W1, b1, h, NN, DD, DD);
    sgemm128<false, 0><<<dim3((NN / 128) * (DD / 128)), blk, 0, stream>>>(
        h, W2, b2, emb, NN, DD, DD);
    // 3) normalize + emit bf16 (h dead -> ehi overlays it)
    rownorm_emit_kernel<<<dim3(NN), blk, 0, stream>>>(emb, ehi);
    // 4) approx sim (bf16 in/out, staged coalesced epilogue) -> out_adj scratch
    simgemm_bf16<<<dim3(4096), blk, 0, stream>>>(ehi, simb);
    // 5) clear edge counters, then fused candidate-select + refine + edge push
    hipMemsetAsync(ecnt, 0, (size_t)NN * sizeof(int), stream);
    topk_refine_kernel<<<dim3(NN), blk, 0, stream>>>(
        simb, emb, tidx, tval, ecnt, elj, elv);
    // 6) fused zero + sort + degree + sparse row write (sim consumed above)
    sort_write_kernel<<<dim3(NN), blk, 0, stream>>>(elj, elv, ecnt, out_adj, sdeg);
    // 7) overflow fixups (no-ops when no row exceeds ECAP)
    ovf_fix_kernel<<<dim3((NN * KTOP + 255) / 256), blk, 0, stream>>>(
        tidx, tval, ecnt, out_adj);
    ovf_deg_kernel<<<dim3(NN), blk, 0, stream>>>(ecnt, out_adj, sdeg);
    // 8-10) x1 = masked @ Wg1 + bg1 via bf16x3 MFMA
    split_kernel<<<dim3(NN * DD / 1024), blk, 0, stream>>>(masked, mhi, mlo);
    wtrans_kernel<<<dim3(DD * HH / 256), blk, 0, stream>>>(Wg1, wt1hi, wt1lo, DD, HH);
    mfma_nt_bias<DD><<<dim3((NN / 128) * (HH / 128)), blk, 0, stream>>>(
        mhi, mlo, wt1hi, wt1lo, bg1, x1, HH);
    // 11) h1 = relu(Ahat @ x1)
    spmm_edges<HH, true><<<dim3(NN), blk, 0, stream>>>(
        elj, elv, ecnt, out_adj, sdeg, x1, h1);
    // 12-14) x2 = h1 @ Wg2 + bg2 via bf16x3 MFMA
    split_kernel<<<dim3(NN * HH / 1024), blk, 0, stream>>>(h1, h1hi, h1lo);
    wtrans_kernel<<<dim3(HH * DD / 256), blk, 0, stream>>>(Wg2, wt2hi, wt2lo, HH, DD);
    mfma_nt_bias<HH><<<dim3((NN / 128) * (DD / 128)), blk, 0, stream>>>(
        h1hi, h1lo, wt2hi, wt2lo, bg2, x2, DD);
    // 15) h3 = Ahat @ x2 -> d_out
    spmm_edges<DD, false><<<dim3(NN), blk, 0, stream>>>(
        elj, elv, ecnt, out_adj, sdeg, x2, out_h3);
}

// Round 9
// 732.402 us; speedup vs baseline: 1.4507x; 1.0031x over previous
//
#include <hip/hip_runtime.h>
#include <cstdint>
#include <cstddef>

#define NN 8192
#define DD 512
#define HH 256
#define KTOP 21
#define CCAP 192   // candidate collection capacity
#define CMIN 48    // minimum candidates (superset of top-21 w/ bf16 margin)
#define ECAP 224   // per-row edge-list capacity
#define NBIN 1024
#define BFLOOR 1   // don't histogram bin 0 (55% of mass -> LDS atomic serialization)
#define NTRI 2080  // 64*65/2 upper-triangle tiles

typedef __attribute__((ext_vector_type(8))) __bf16 bf16x8;
typedef __attribute__((ext_vector_type(4))) float f32x4;

__device__ __forceinline__ unsigned short f2bf(float x) {
    unsigned u = __float_as_uint(x);
    u += 0x7fffu + ((u >> 16) & 1u);
    return (unsigned short)(u >> 16);
}
__device__ __forceinline__ float bf2f(unsigned short h) {
    return __uint_as_float(((unsigned)h) << 16);
}
// order-preserving key: monotone map float -> uint (used by sort_write)
__device__ __forceinline__ unsigned ordkey(float x) {
    unsigned b = __float_as_uint(x);
    return b ^ (((int)b >> 31) | 0x80000000u);
}
// LDS column swizzle for the 64x128-short epilogue stage buffer
__device__ __forceinline__ int swzc(int r, int c) { return c ^ ((r & 7) << 4); }

#define GLD16(gp, lp) __builtin_amdgcn_global_load_lds( \
    (const __attribute__((address_space(1))) unsigned int*)(gp), \
    (__attribute__((address_space(3))) unsigned int*)(lp), 16, 0, 0)

// ---------------------------------------------------------------------------
// fp32 SGEMM: GEMM1/2 (emb path must stay fp32-exact for selection)
// ---------------------------------------------------------------------------
template<bool TRANSB, int ACT>
__global__ __launch_bounds__(256)
void sgemm128(const float* __restrict__ A, const float* __restrict__ B,
              const float* __restrict__ bias, float* __restrict__ C,
              int M, int N, int K) {
    constexpr int BM = 128, BN = 128, BK = 16;
    __shared__ float As[BK][BM + 4];
    __shared__ float Bs[BK][BN + 4];

    const int tiles_n = N / BN;
    const int by = blockIdx.x / tiles_n;
    const int bx = blockIdx.x % tiles_n;
    const int row0 = by * BM, col0 = bx * BN;
    const int tid = threadIdx.x;
    const int tx = tid & 15, ty = tid >> 4;

    float acc[8][8];
#pragma unroll
    for (int m = 0; m < 8; ++m)
#pragma unroll
        for (int n = 0; n < 8; ++n) acc[m][n] = 0.f;

    for (int k0 = 0; k0 < K; k0 += BK) {
#pragma unroll
        for (int l = 0; l < 2; ++l) {
            int f = tid + l * 256;
            int r = f >> 2, c4 = f & 3;
            float4 v = *reinterpret_cast<const float4*>(
                A + (size_t)(row0 + r) * K + k0 + c4 * 4);
            As[c4 * 4 + 0][r] = v.x;
            As[c4 * 4 + 1][r] = v.y;
            As[c4 * 4 + 2][r] = v.z;
            As[c4 * 4 + 3][r] = v.w;
        }
        if (TRANSB) {
#pragma unroll
            for (int l = 0; l < 2; ++l) {
                int f = tid + l * 256;
                int r = f >> 2, c4 = f & 3;
                float4 v = *reinterpret_cast<const float4*>(
                    B + (size_t)(col0 + r) * K + k0 + c4 * 4);
                Bs[c4 * 4 + 0][r] = v.x;
                Bs[c4 * 4 + 1][r] = v.y;
                Bs[c4 * 4 + 2][r] = v.z;
                Bs[c4 * 4 + 3][r] = v.w;
            }
        } else {
#pragma unroll
            for (int l = 0; l < 2; ++l) {
                int f = tid + l * 256;
                int kr = f >> 5, n4 = f & 31;
                *reinterpret_cast<float4*>(&Bs[kr][n4 * 4]) =
                    *reinterpret_cast<const float4*>(
                        B + (size_t)(k0 + kr) * N + col0 + n4 * 4);
            }
        }
        __syncthreads();

#pragma unroll
        for (int kk = 0; kk < BK; ++kk) {
            float a[8], b[8];
            *(float4*)&a[0] = *(const float4*)&As[kk][ty * 8];
            *(float4*)&a[4] = *(const float4*)&As[kk][ty * 8 + 4];
            *(float4*)&b[0] = *(const float4*)&Bs[kk][tx * 8];
            *(float4*)&b[4] = *(const float4*)&Bs[kk][tx * 8 + 4];
#pragma unroll
            for (int m = 0; m < 8; ++m)
#pragma unroll
                for (int n = 0; n < 8; ++n)
                    acc[m][n] = fmaf(a[m], b[n], acc[m][n]);
        }
        __syncthreads();
    }

    const int crow = row0 + ty * 8;
    const int ccol = col0 + tx * 8;
    float bv[8];
#pragma unroll
    for (int n = 0; n < 8; ++n) bv[n] = bias ? bias[ccol + n] : 0.f;
#pragma unroll
    for (int m = 0; m < 8; ++m) {
        float o[8];
#pragma unroll
        for (int n = 0; n < 8; ++n) {
            float t = acc[m][n] + bv[n];
            if (ACT == 1) t = fmaxf(t, 0.f);
            o[n] = t;
        }
        *reinterpret_cast<float4*>(C + (size_t)(crow + m) * N + ccol)     = *(float4*)&o[0];
        *reinterpret_cast<float4*>(C + (size_t)(crow + m) * N + ccol + 4) = *(float4*)&o[4];
    }
}

// ---------------------------------------------------------------------------
// Row L2-normalize + emit bf16 copy + clear ecnt (fold the memset launch in)
// ---------------------------------------------------------------------------
__global__ __launch_bounds__(256)
void rownorm_emit_kernel(float* __restrict__ emb, unsigned short* __restrict__ ehi,
                         int* __restrict__ ecnt) {
    const int row = blockIdx.x, tid = threadIdx.x;
    float* rp = emb + (size_t)row * DD;
    float v0 = rp[tid], v1 = rp[tid + 256];
    float sum = v0 * v0 + v1 * v1;
#pragma unroll
    for (int off = 32; off > 0; off >>= 1) sum += __shfl_down(sum, off, 64);
    __shared__ float ws[4];
    __shared__ float sc_sh;
    if ((tid & 63) == 0) ws[tid >> 6] = sum;
    __syncthreads();
    if (tid == 0) {
        float n = sqrtf(ws[0] + ws[1] + ws[2] + ws[3]);
        sc_sh = 1.0f / fmaxf(n, 1e-12f);
        ecnt[row] = 0;
    }
    __syncthreads();
    float sc = sc_sh;
    v0 *= sc; v1 *= sc;
    rp[tid] = v0;
    rp[tid + 256] = v1;
    ehi[(size_t)row * DD + tid]       = f2bf(v0);
    ehi[(size_t)row * DD + tid + 256] = f2bf(v1);
}

// ---------------------------------------------------------------------------
// Split fp32 -> (hi, lo) bf16 pair
// ---------------------------------------------------------------------------
__global__ __launch_bounds__(256)
void split_kernel(const float* __restrict__ e, unsigned short* __restrict__ hi,
                  unsigned short* __restrict__ lo) {
    const int i = (blockIdx.x * 256 + threadIdx.x) * 4;
    float4 v = *reinterpret_cast<const float4*>(e + i);
    ushort4 h, l;
    h.x = f2bf(v.x); l.x = f2bf(v.x - bf2f(h.x));
    h.y = f2bf(v.y); l.y = f2bf(v.y - bf2f(h.y));
    h.z = f2bf(v.z); l.z = f2bf(v.z - bf2f(h.z));
    h.w = f2bf(v.w); l.w = f2bf(v.w - bf2f(h.w));
    *reinterpret_cast<ushort4*>(hi + i) = h;
    *reinterpret_cast<ushort4*>(lo + i) = l;
}

// ---------------------------------------------------------------------------
// Transpose + split BOTH weight matrices in one launch.
// Wg1 [DD,HH] -> t1 [HH,DD]; Wg2 [HH,DD] -> t2 [DD,HH].
// ---------------------------------------------------------------------------
__global__ __launch_bounds__(256)
void wtrans2_kernel(const float* __restrict__ Wg1, const float* __restrict__ Wg2,
                    unsigned short* __restrict__ t1h, unsigned short* __restrict__ t1l,
                    unsigned short* __restrict__ t2h, unsigned short* __restrict__ t2l) {
    int t = blockIdx.x * 256 + threadIdx.x;
    if (t < DD * HH) {
        int k = t / HH, n = t - k * HH;
        float x = Wg1[t];
        unsigned short h = f2bf(x);
        t1h[(size_t)n * DD + k] = h;
        t1l[(size_t)n * DD + k] = f2bf(x - bf2f(h));
    } else {
        int u = t - DD * HH;
        int k = u / DD, n = u - k * DD;
        float x = Wg2[u];
        unsigned short h = f2bf(x);
        t2h[(size_t)n * HH + k] = h;
        t2l[(size_t)n * HH + k] = f2bf(x - bf2f(h));
    }
}

// ---------------------------------------------------------------------------
// approx sim = Ehi * Ehi^T — UPPER-TRIANGLE tiles only (sim is symmetric and
// tile (i,j) is bitwise-equal to (j,i)); each off-diagonal tile is written
// twice (direct + transposed) through a swizzled LDS stage. Halves MFMA work
// and A/B panel fetch; write volume unchanged. bf16 output.
// ---------------------------------------------------------------------------
__global__ __launch_bounds__(256)
void simgemm_bf16_tri(const unsigned short* __restrict__ Ehi,
                      unsigned short* __restrict__ Cb) {
    // NTRI = 2080 tiles; 2080 % 8 == 0 -> simple XCD swizzle is bijective
    const int bid = blockIdx.x;
    const int swz = (bid & 7) * (NTRI / 8) + (bid >> 3);
    int t = swz, by = 0;
    while (t >= 64 - by) { t -= 64 - by; ++by; }   // triangular decode (scalar)
    const int bx = by + t;

    __shared__ unsigned short SB[8192];   // 16 KB: A/B staging, then epilogue
    unsigned short* Ah = SB;              // 128*32
    unsigned short* Bh = SB + 4096;       // 128*32

    const int tid = threadIdx.x, lane = tid & 63, wid = tid >> 6;
    const int wm = wid >> 1, wn = wid & 1;
    const int fr = lane & 15, fq = lane >> 4;
    const int lrow = lane >> 2;
    const int lcol8 = (lane & 3) * 8;

    const size_t arow0 = (size_t)by * 128;
    const size_t brow0 = (size_t)bx * 128;

    f32x4 acc[4][4];
#pragma unroll
    for (int m = 0; m < 4; ++m)
#pragma unroll
        for (int n = 0; n < 4; ++n) acc[m][n] = (f32x4){0.f, 0.f, 0.f, 0.f};

    for (int k0 = 0; k0 < DD; k0 += 32) {
#pragma unroll
        for (int i = 0; i < 2; ++i) {
            const int chunk = wid + i * 4;
            const int grow = chunk * 16 + lrow;
            GLD16(Ehi + (arow0 + grow) * DD + (k0 + lcol8), Ah + chunk * 512);
            GLD16(Ehi + (brow0 + grow) * DD + (k0 + lcol8), Bh + chunk * 512);
        }
        __syncthreads();

        bf16x8 ah[4], bh[4];
#pragma unroll
        for (int mf = 0; mf < 4; ++mf)
            ah[mf] = *(const bf16x8*)&Ah[(wm * 64 + mf * 16 + fr) * 32 + fq * 8];
#pragma unroll
        for (int nf = 0; nf < 4; ++nf)
            bh[nf] = *(const bf16x8*)&Bh[(wn * 64 + nf * 16 + fr) * 32 + fq * 8];
#pragma unroll
        for (int mf = 0; mf < 4; ++mf)
#pragma unroll
            for (int nf = 0; nf < 4; ++nf)
                acc[mf][nf] = __builtin_amdgcn_mfma_f32_16x16x32_bf16(ah[mf], bh[nf], acc[mf][nf], 0, 0, 0);
        __syncthreads();
    }

    // epilogue: two 64-row phases. Stage bf16 (swizzled), then:
    //  (a) direct write rows [arow0+ph*64, +64) x cols [bx*128, +128)
    //  (b) if bx!=by: transposed write rows [brow0, +128) x cols [arow0+ph*64, +64)
#pragma unroll
    for (int ph = 0; ph < 2; ++ph) {
        if (wm == ph) {
#pragma unroll
            for (int mf = 0; mf < 4; ++mf)
#pragma unroll
                for (int nf = 0; nf < 4; ++nf)
#pragma unroll
                    for (int r2 = 0; r2 < 4; ++r2) {
                        const int r = mf * 16 + fq * 4 + r2;
                        const int c = wn * 64 + nf * 16 + fr;
                        SB[r * 128 + swzc(r, c)] = f2bf(acc[mf][nf][r2]);
                    }
        }
        __syncthreads();
        // (a) direct, coalesced 16B/lane
#pragma unroll
        for (int it = 0; it < 4; ++it) {
            int flat = it * 256 + tid;
            int rowL = flat >> 4, cc = flat & 15;
            *reinterpret_cast<uint4*>(
                &Cb[(arow0 + ph * 64 + rowL) * NN + (size_t)bx * 128 + cc * 8]) =
                *reinterpret_cast<const uint4*>(&SB[rowL * 128 + swzc(rowL, cc * 8)]);
        }
        // (b) transposed mirror (L2 merges the 16B stores into full lines)
        if (bx != by) {
#pragma unroll
            for (int it = 0; it < 4; ++it) {
                int w = it * 256 + tid;
                int c = w & 127, s = w >> 7;        // c: tile col; s*8: row chunk
                unsigned short vals[8];
#pragma unroll
                for (int k = 0; k < 8; ++k) {
                    const int r = s * 8 + k;
                    vals[k] = SB[r * 128 + swzc(r, c)];
                }
                *reinterpret_cast<uint4*>(
                    &Cb[(brow0 + c) * NN + arow0 + ph * 64 + s * 8]) =
                    *reinterpret_cast<const uint4*>(&vals[0]);
            }
        }
        __syncthreads();
    }
}

// ---------------------------------------------------------------------------
// bf16x3 MFMA GEMM (NT) with bias: x1/x2 path
// ---------------------------------------------------------------------------
template<int KDIM>
__global__ __launch_bounds__(256)
void mfma_nt_bias(const unsigned short* __restrict__ Ahi,
                  const unsigned short* __restrict__ Alo,
                  const unsigned short* __restrict__ Bhi,
                  const unsigned short* __restrict__ Blo,
                  const float* __restrict__ bias, float* __restrict__ C, int N) {
    const int tiles_n = N / 128;
    const int by = blockIdx.x / tiles_n, bx = blockIdx.x % tiles_n;

    __shared__ unsigned short Ah[128 * 32];
    __shared__ unsigned short Al[128 * 32];
    __shared__ unsigned short Bh[128 * 32];
    __shared__ unsigned short Bl[128 * 32];

    const int tid = threadIdx.x, lane = tid & 63, wid = tid >> 6;
    const int wm = wid >> 1, wn = wid & 1;
    const int fr = lane & 15, fq = lane >> 4;
    const int lrow = lane >> 2;
    const int lcol8 = (lane & 3) * 8;

    const size_t arow0 = (size_t)by * 128;
    const size_t brow0 = (size_t)bx * 128;

    f32x4 acc[4][4];
#pragma unroll
    for (int m = 0; m < 4; ++m)
#pragma unroll
        for (int n = 0; n < 4; ++n) acc[m][n] = (f32x4){0.f, 0.f, 0.f, 0.f};

    for (int k0 = 0; k0 < KDIM; k0 += 32) {
#pragma unroll
        for (int i = 0; i < 2; ++i) {
            const int chunk = wid + i * 4;
            const int grow = chunk * 16 + lrow;
            GLD16(Ahi + (arow0 + grow) * KDIM + (k0 + lcol8), Ah + chunk * 512);
            GLD16(Alo + (arow0 + grow) * KDIM + (k0 + lcol8), Al + chunk * 512);
            GLD16(Bhi + (brow0 + grow) * KDIM + (k0 + lcol8), Bh + chunk * 512);
            GLD16(Blo + (brow0 + grow) * KDIM + (k0 + lcol8), Bl + chunk * 512);
        }
        __syncthreads();

        bf16x8 ah[4], al[4], bh[4], bl[4];
#pragma unroll
        for (int mf = 0; mf < 4; ++mf) {
            const int r = wm * 64 + mf * 16 + fr;
            ah[mf] = *(const bf16x8*)&Ah[r * 32 + fq * 8];
            al[mf] = *(const bf16x8*)&Al[r * 32 + fq * 8];
        }
#pragma unroll
        for (int nf = 0; nf < 4; ++nf) {
            const int r = wn * 64 + nf * 16 + fr;
            bh[nf] = *(const bf16x8*)&Bh[r * 32 + fq * 8];
            bl[nf] = *(const bf16x8*)&Bl[r * 32 + fq * 8];
        }
#pragma unroll
        for (int mf = 0; mf < 4; ++mf)
#pragma unroll
            for (int nf = 0; nf < 4; ++nf) {
                acc[mf][nf] = __builtin_amdgcn_mfma_f32_16x16x32_bf16(ah[mf], bh[nf], acc[mf][nf], 0, 0, 0);
                acc[mf][nf] = __builtin_amdgcn_mfma_f32_16x16x32_bf16(ah[mf], bl[nf], acc[mf][nf], 0, 0, 0);
                acc[mf][nf] = __builtin_amdgcn_mfma_f32_16x16x32_bf16(al[mf], bh[nf], acc[mf][nf], 0, 0, 0);
            }
        __syncthreads();
    }

#pragma unroll
    for (int mf = 0; mf < 4; ++mf) {
#pragma unroll
        for (int nf = 0; nf < 4; ++nf) {
            const size_t row = arow0 + wm * 64 + mf * 16 + fq * 4;
            const int col = bx * 128 + wn * 64 + nf * 16 + fr;
            const float bv = bias[col];
#pragma unroll
            for (int r2 = 0; r2 < 4; ++r2)
                C[(row + r2) * N + col] = acc[mf][nf][r2] + bv;
        }
    }
}

// ---------------------------------------------------------------------------
// FUSED: histogram candidate selection + exact fp32 refine + top-21 + edge push
// ---------------------------------------------------------------------------
__global__ __launch_bounds__(256)
void topk_refine_kernel(const unsigned short* __restrict__ simb,
                        const float* __restrict__ emb,
                        int* __restrict__ tidx, float* __restrict__ tval,
                        int* __restrict__ ecnt, int* __restrict__ elj,
                        float* __restrict__ elv) {
    const int row = blockIdx.x;
    const int tid = threadIdx.x;
    const int lane = tid & 63, wave = tid >> 6;

    // ---- phase 1: load row, histogram, threshold ----
    const uint4* rp = reinterpret_cast<const uint4*>(simb + (size_t)row * NN);
    uint4 q[4];
#pragma unroll
    for (int t = 0; t < 4; ++t) q[t] = rp[t * 256 + tid];
    unsigned pk[16];
#pragma unroll
    for (int t = 0; t < 4; ++t) {
        pk[t * 4 + 0] = q[t].x; pk[t * 4 + 1] = q[t].y;
        pk[t * 4 + 2] = q[t].z; pk[t * 4 + 3] = q[t].w;
    }

    __shared__ int hist[NBIN];
    for (int b = tid; b < NBIN; b += 256) hist[b] = 0;
    __syncthreads();

    short bins[32];
#pragma unroll
    for (int u = 0; u < 16; ++u) {
        float flo = __uint_as_float(pk[u] << 16);
        float fhi = __uint_as_float(pk[u] & 0xFFFF0000u);
        int blo = (int)(flo * (float)NBIN); blo = max(0, min(NBIN - 1, blo));
        int bhi = (int)(fhi * (float)NBIN); bhi = max(0, min(NBIN - 1, bhi));
        bins[u * 2]     = (short)blo;
        bins[u * 2 + 1] = (short)bhi;
        if (blo >= BFLOOR) atomicAdd(&hist[blo], 1);
        if (bhi >= BFLOOR) atomicAdd(&hist[bhi], 1);
    }
    __syncthreads();

    __shared__ int s_bstar;
    if (wave == 0) {
        int cum = 0, found = -1;
        for (int c0 = NBIN - 1; c0 >= 0 && found < 0; c0 -= 64) {
            int b = c0 - lane;
            int cnt = (b >= 0) ? hist[b] : 0;
            int sc = cnt;
#pragma unroll
            for (int off = 1; off < 64; off <<= 1) {
                int o = __shfl_up(sc, off, 64);
                if (lane >= off) sc += o;
            }
            int chunk_total = __shfl(sc, 63, 64);
            bool hit = (cum + sc >= CMIN);
            unsigned long long mh = __ballot(hit);
            if (mh) found = c0 - (__ffsll((long long)mh) - 1);
            else cum += chunk_total;
        }
        if (found < 0) found = 0;
        if (lane == 0) s_bstar = found;
    }
    __syncthreads();
    const int bstar = s_bstar;

    // ---- phase 2: deterministic compaction of candidates into LDS ----
    __shared__ int s_cand[CCAP];
    int cnt = 0;
#pragma unroll
    for (int i = 0; i < 32; ++i) cnt += (bins[i] >= bstar) ? 1 : 0;
    int sc = cnt;
#pragma unroll
    for (int off = 1; off < 64; off <<= 1) {
        int o = __shfl_up(sc, off, 64);
        if (lane >= off) sc += o;
    }
    __shared__ int wtot[4];
    if (lane == 63) wtot[wave] = sc;
    __syncthreads();
    int base = sc - cnt;
#pragma unroll
    for (int w = 0; w < 4; ++w)
        if (w < wave) base += wtot[w];
    int total = wtot[0] + wtot[1] + wtot[2] + wtot[3];

    int pos = base;
#pragma unroll
    for (int u = 0; u < 16; ++u) {
#pragma unroll
        for (int h = 0; h < 2; ++h) {
            if (bins[u * 2 + h] >= bstar) {
                if (pos < CCAP)
                    s_cand[pos] = ((u >> 2) * 256 + tid) * 8 + (u & 3) * 2 + h;
                pos++;
            }
        }
    }
    __syncthreads();
    const int ncand = min(total, CCAP);

    // ---- phase 3: exact fp32 dots for candidates ----
    __shared__ float sval[CCAP];
    __shared__ int   sidx[CCAP];
    const float* ei = emb + (size_t)row * DD;
    float4 a0 = reinterpret_cast<const float4*>(ei)[lane * 2];
    float4 a1 = reinterpret_cast<const float4*>(ei)[lane * 2 + 1];

    for (int base2 = wave * 2; base2 < ncand; base2 += 8) {
#pragma unroll
        for (int qq = 0; qq < 2; ++qq) {
            int c = base2 + qq;
            if (c >= ncand) break;
            const int j = s_cand[c];
            const float* ej = emb + (size_t)j * DD;
            float4 b0 = reinterpret_cast<const float4*>(ej)[lane * 2];
            float4 b1 = reinterpret_cast<const float4*>(ej)[lane * 2 + 1];
            float s = 0.f;
            s = fmaf(a0.x, b0.x, s); s = fmaf(a0.y, b0.y, s);
            s = fmaf(a0.z, b0.z, s); s = fmaf(a0.w, b0.w, s);
            s = fmaf(a1.x, b1.x, s); s = fmaf(a1.y, b1.y, s);
            s = fmaf(a1.z, b1.z, s); s = fmaf(a1.w, b1.w, s);
#pragma unroll
            for (int off = 32; off > 0; off >>= 1) s += __shfl_xor(s, off, 64);
            if (lane == 0) { sval[c] = s; sidx[c] = j; }
        }
    }
    __syncthreads();

    // ---- phase 4: wave0 selects top-21 (value desc, idx asc) ----
    __shared__ float selv[KTOP];
    __shared__ int   seli[KTOP];
    if (wave == 0) {
        float v[3]; int id[3];
#pragma unroll
        for (int k = 0; k < 3; ++k) {
            int s = lane + 64 * k;
            if (s < ncand) { v[k] = sval[s]; id[k] = sidx[s]; }
            else           { v[k] = -INFINITY; id[k] = 0x7fffffff; }
        }
#pragma unroll 1
        for (int sel = 0; sel < KTOP; ++sel) {
            float bv = v[0]; int bi = id[0];
#pragma unroll
            for (int k = 1; k < 3; ++k)
                if (v[k] > bv || (v[k] == bv && id[k] < bi)) { bv = v[k]; bi = id[k]; }
#pragma unroll
            for (int off = 1; off < 64; off <<= 1) {
                float ov = __shfl_xor(bv, off, 64);
                int   oi = __shfl_xor(bi, off, 64);
                if (ov > bv || (ov == bv && oi < bi)) { bv = ov; bi = oi; }
            }
            if (lane == 0) { selv[sel] = bv; seli[sel] = bi; }
#pragma unroll
            for (int k = 0; k < 3; ++k)
                if (id[k] == bi) { v[k] = -INFINITY; id[k] = 0x7fffffff; }
        }
    }
    __syncthreads();

    // ---- phase 5: write topk + push edges into lists ----
    if (tid < KTOP) {
        float bv = selv[tid];
        int   bi = seli[tid];
        tval[(size_t)row * KTOP + tid] = bv;
        tidx[(size_t)row * KTOP + tid] = bi;
        if (bi != row && bi >= 0 && bi < NN && bv > 0.f) {
            float v = bv * 0.5f;
            int pi = atomicAdd(ecnt + row, 1);
            if (pi < ECAP) { elj[(size_t)row * ECAP + pi] = bi; elv[(size_t)row * ECAP + pi] = v; }
            int pj = atomicAdd(ecnt + bi, 1);
            if (pj < ECAP) { elj[(size_t)bi * ECAP + pj] = row; elv[(size_t)bi * ECAP + pj] = v; }
        }
    }
}

// ---------------------------------------------------------------------------
// FUSED adjacency materialization: zero row + sort edges + sdeg + sparse write.
// ---------------------------------------------------------------------------
__global__ __launch_bounds__(256)
void sort_write_kernel(int* __restrict__ ej, float* __restrict__ ev,
                       const int* __restrict__ ecnt,
                       float* __restrict__ adj, float* __restrict__ sdeg) {
    const int row = blockIdx.x, tid = threadIdx.x;
    const int nraw = ecnt[row];

    float4* out4 = reinterpret_cast<float4*>(adj + (size_t)row * NN);
    const float4 z = {0.f, 0.f, 0.f, 0.f};
#pragma unroll
    for (int f = tid; f < NN / 4; f += 256) out4[f] = z;

    if (nraw > ECAP) return;   // overflow: fixup kernels handle fill + degree

    const int n = nraw;
    __shared__ int   lj[ECAP];
    __shared__ float lv[ECAP];
    __shared__ unsigned long long skey[ECAP];
    __shared__ int   oj[ECAP];
    __shared__ float ov[ECAP];
    if (tid < n) {
        int  jv = ej[(size_t)row * ECAP + tid];
        float vv = ev[(size_t)row * ECAP + tid];
        lj[tid] = jv; lv[tid] = vv;
        skey[tid] = ((unsigned long long)(unsigned)jv << 32) | (unsigned long long)ordkey(vv);
    }
    __syncthreads();
    if (tid < n) {
        unsigned long long mk = skey[tid];
        int rank = 0;
        for (int u = 0; u < n; ++u) {
            unsigned long long ku = skey[u];
            rank += (ku < mk || (ku == mk && u < tid)) ? 1 : 0;
        }
        oj[rank] = lj[tid];
        ov[rank] = lv[tid];
    }
    __syncthreads();
    if (tid < n) {
        ej[(size_t)row * ECAP + tid] = oj[tid];
        ev[(size_t)row * ECAP + tid] = ov[tid];
    }
    if (tid == 0) {
        float deg = 1.0f;
        for (int e = 0; e < n; ++e) deg += ov[e];
        sdeg[row] = 1.0f / (sqrtf(deg) + 1e-10f);
    }
    __syncthreads();
    if (tid < n) {
        int j = oj[tid];
        if (tid == 0 || oj[tid - 1] != j) {
            float s = ov[tid];
            if (tid + 1 < n && oj[tid + 1] == j) s += ov[tid + 1];
            adj[(size_t)row * NN + j] = s;
        }
    }
}

// ---------------------------------------------------------------------------
// Overflow fixups (no-ops when no row exceeds ECAP)
// ---------------------------------------------------------------------------
__global__ __launch_bounds__(256)
void ovf_fix_kernel(const int* __restrict__ tidx, const float* __restrict__ tval,
                    const int* __restrict__ ecnt, float* __restrict__ adj) {
    int t = blockIdx.x * 256 + threadIdx.x;
    if (t >= NN * KTOP) return;
    int i = t / KTOP;
    int j = tidx[t];
    if (j == i || j < 0) return;
    float v = tval[t];
    if (v <= 0.f) return;
    v *= 0.5f;
    if (ecnt[i] > ECAP) atomicAdd(adj + (size_t)i * NN + j, v);
    if (ecnt[j] > ECAP) atomicAdd(adj + (size_t)j * NN + i, v);
}

__global__ __launch_bounds__(256)
void ovf_deg_kernel(const int* __restrict__ ecnt, const float* __restrict__ adj,
                    float* __restrict__ sdeg) {
    const int row = blockIdx.x, tid = threadIdx.x;
    if (ecnt[row] <= ECAP) return;
    const int lane = tid & 63, wave = tid >> 6;
    const float4* rp = reinterpret_cast<const float4*>(adj + (size_t)row * NN);
    float sum = 0.f;
    for (int f = tid; f < NN / 4; f += 256) {
        float4 v = rp[f];
        sum += (v.x + v.y) + (v.z + v.w);
    }
#pragma unroll
    for (int off = 32; off > 0; off >>= 1) sum += __shfl_down(sum, off, 64);
    __shared__ float ws[4];
    if (lane == 0) ws[wave] = sum;
    __syncthreads();
    if (tid == 0)
        sdeg[row] = 1.0f / (sqrtf(1.0f + ws[0] + ws[1] + ws[2] + ws[3]) + 1e-10f);
}

// ---------------------------------------------------------------------------
// SpMM from sorted edge lists (deterministic); dense-scan fallback on ovf.
// ---------------------------------------------------------------------------
template<int COLS, bool DORELU>
__global__ __launch_bounds__(256)
void spmm_edges(const int* __restrict__ ej, const float* __restrict__ ev,
                const int* __restrict__ ecnt, const float* __restrict__ adj,
                const float* __restrict__ sdeg,
                const float* __restrict__ X, float* __restrict__ Y) {
    constexpr int CPT = COLS / 256;
    const int i = blockIdx.x;
    const int tid = threadIdx.x;
    const int lane = tid & 63, wave = tid >> 6;
    const float si = sdeg[i];
    const int nraw = ecnt[i];

    float acc[CPT];
#pragma unroll
    for (int c = 0; c < CPT; ++c) acc[c] = 0.f;

    if (nraw <= ECAP) {
        __shared__ int   s_j[ECAP];
        __shared__ float s_w[ECAP];
        if (tid < nraw) {
            int j = ej[(size_t)i * ECAP + tid];
            s_j[tid] = j;
            s_w[tid] = ev[(size_t)i * ECAP + tid] * sdeg[j];
        }
        __syncthreads();
#pragma unroll 4
        for (int e = 0; e < nraw; ++e) {
            int j = s_j[e];
            float we = s_w[e];
#pragma unroll
            for (int c = 0; c < CPT; ++c)
                acc[c] += we * X[(size_t)j * COLS + tid + c * 256];
        }
    } else {
        __shared__ int   s_j[256];
        __shared__ float s_w[256];
        __shared__ int   s_cnt[4];
        const float* rowp = adj + (size_t)i * NN;
        for (int j0 = 0; j0 < NN; j0 += 256) {
            float w = rowp[j0 + tid];
            bool nz = (w != 0.f);
            unsigned long long m = __ballot(nz);
            unsigned long long ltmask = (lane == 0) ? 0ull : (~0ull >> (64 - lane));
            int pre = __popcll(m & ltmask);
            if (lane == 0) s_cnt[wave] = __popcll(m);
            __syncthreads();
            int base = 0;
#pragma unroll
            for (int q = 0; q < 4; ++q)
                if (q < wave) base += s_cnt[q];
            int total = s_cnt[0] + s_cnt[1] + s_cnt[2] + s_cnt[3];
            if (nz) {
                int p = base + pre;
                s_j[p] = j0 + tid;
                s_w[p] = w * sdeg[j0 + tid];
            }
            __syncthreads();
            for (int e = 0; e < total; ++e) {
                int j = s_j[e];
                float we = s_w[e];
#pragma unroll
                for (int c = 0; c < CPT; ++c)
                    acc[c] += we * X[(size_t)j * COLS + tid + c * 256];
            }
            __syncthreads();
        }
    }

#pragma unroll
    for (int c = 0; c < CPT; ++c) {
        float val = si * (acc[c] + si * X[(size_t)i * COLS + tid + c * 256]);
        if (DORELU) val = fmaxf(val, 0.f);
        Y[(size_t)i * COLS + tid + c * 256] = val;
    }
}

// ---------------------------------------------------------------------------
extern "C" void kernel_launch(void* const* d_in, const int* in_sizes, int n_in,
                              void* d_out, int out_size, void* d_ws, size_t ws_size,
                              hipStream_t stream) {
    const float* features = (const float*)d_in[0];
    const float* masked   = (const float*)d_in[1];
    const float* W1  = (const float*)d_in[2];
    const float* b1  = (const float*)d_in[3];
    const float* W2  = (const float*)d_in[4];
    const float* b2  = (const float*)d_in[5];
    const float* Wg1 = (const float*)d_in[6];
    const float* bg1 = (const float*)d_in[7];
    const float* Wg2 = (const float*)d_in[8];
    const float* bg2 = (const float*)d_in[9];

    float* out_h3  = (float*)d_out;                      // [NN, DD]
    float* out_adj = (float*)d_out + (size_t)NN * DD;    // [NN, NN] (bf16 sim scratch too)
    unsigned short* simb = (unsigned short*)out_adj;     // bf16 sim view

    float* Areg = (float*)d_ws;
    float* Breg = Areg + (size_t)NN * DD;
    float* tail = Breg + (size_t)NN * DD;

    float* h    = Areg;
    unsigned short* ehi = (unsigned short*)Areg;          // NN*DD bf16
    unsigned short* mhi = (unsigned short*)Areg;          // NN*DD bf16
    unsigned short* mlo = mhi + (size_t)NN * DD;
    unsigned short* h1hi = (unsigned short*)Areg;         // NN*HH bf16
    unsigned short* h1lo = h1hi + (size_t)NN * HH;

    float* emb = Breg;
    float* x1  = Breg;                                    // [NN,HH] fp32
    float* h1  = Breg + (size_t)NN * HH;                  // [NN,HH] fp32
    float* x2  = Breg;                                    // [NN,DD] fp32

    float* tval = tail;                                   // NN*KTOP
    int*   tidx = (int*)(tval + (size_t)NN * KTOP);       // NN*KTOP
    float* sdeg = (float*)(tidx + (size_t)NN * KTOP);     // NN
    int*   ecnt = (int*)(sdeg + NN);                      // NN
    int*   elj  = ecnt + NN;                              // NN*ECAP
    float* elv  = (float*)(elj + (size_t)NN * ECAP);      // NN*ECAP
    unsigned short* wt1hi = (unsigned short*)(elv + (size_t)NN * ECAP); // HH*DD
    unsigned short* wt1lo = wt1hi + (size_t)HH * DD;
    unsigned short* wt2hi = wt1lo + (size_t)HH * DD;      // DD*HH
    unsigned short* wt2lo = wt2hi + (size_t)DD * HH;

    dim3 blk(256);

    // 1-2) MLP (fp32 — selection accuracy depends on emb)
    sgemm128<false, 1><<<dim3((NN / 128) * (DD / 128)), blk, 0, stream>>>(
        features, W1, b1, h, NN, DD, DD);
    sgemm128<false, 0><<<dim3((NN / 128) * (DD / 128)), blk, 0, stream>>>(
        h, W2, b2, emb, NN, DD, DD);
    // 3) normalize + emit bf16 + clear ecnt (h dead -> ehi overlays it)
    rownorm_emit_kernel<<<dim3(NN), blk, 0, stream>>>(emb, ehi, ecnt);
    // 4) approx sim: upper-triangle tiles, mirrored write -> out_adj scratch
    simgemm_bf16_tri<<<dim3(NTRI), blk, 0, stream>>>(ehi, simb);
    // 5) fused candidate-select + refine + top-21 + edge push
    topk_refine_kernel<<<dim3(NN), blk, 0, stream>>>(
        simb, emb, tidx, tval, ecnt, elj, elv);
    // 6) fused zero + sort + degree + sparse row write
    sort_write_kernel<<<dim3(NN), blk, 0, stream>>>(elj, elv, ecnt, out_adj, sdeg);
    // 7) overflow fixups (no-ops when no row exceeds ECAP)
    ovf_fix_kernel<<<dim3((NN * KTOP + 255) / 256), blk, 0, stream>>>(
        tidx, tval, ecnt, out_adj);
    ovf_deg_kernel<<<dim3(NN), blk, 0, stream>>>(ecnt, out_adj, sdeg);
    // 8-10) x1 = masked @ Wg1 + bg1 via bf16x3 MFMA
    split_kernel<<<dim3(NN * DD / 1024), blk, 0, stream>>>(masked, mhi, mlo);
    wtrans2_kernel<<<dim3(2 * DD * HH / 256), blk, 0, stream>>>(
        Wg1, Wg2, wt1hi, wt1lo, wt2hi, wt2lo);
    mfma_nt_bias<DD><<<dim3((NN / 128) * (HH / 128)), blk, 0, stream>>>(
        mhi, mlo, wt1hi, wt1lo, bg1, x1, HH);
    // 11) h1 = relu(Ahat @ x1)
    spmm_edges<HH, true><<<dim3(NN), blk, 0, stream>>>(
        elj, elv, ecnt, out_adj, sdeg, x1, h1);
    // 12-13) x2 = h1 @ Wg2 + bg2 via bf16x3 MFMA
    split_kernel<<<dim3(NN * HH / 1024), blk, 0, stream>>>(h1, h1hi, h1lo);
    mfma_nt_bias<HH><<<dim3((NN / 128) * (DD / 128)), blk, 0, stream>>>(
        h1hi, h1lo, wt2hi, wt2lo, bg2, x2, DD);
    // 14) h3 = Ahat @ x2 -> d_out
    spmm_edges<DD, false><<<dim3(NN), blk, 0, stream>>>(
        elj, elv, ecnt, out_adj, sdeg, x2, out_h3);
}